// Round 3
// baseline (1488.789 us; speedup 1.0000x reference)
//
#include <hip/hip_runtime.h>
#include <hip/hip_bf16.h>
#include <math.h>

typedef __attribute__((ext_vector_type(4))) float f32x4;
typedef __attribute__((ext_vector_type(8))) short s16x8;

#define MAXD 192  // fast-path degree cap for fused softmax (LDS alpha buffer)

// ---------------- CSR-by-dst construction ----------------

__global__ void zero2_kernel(int* __restrict__ a, int* __restrict__ b, int n) {
    int i = blockIdx.x * blockDim.x + threadIdx.x;
    if (i < n) { a[i] = 0; b[i] = 0; }
}

__global__ void hist_kernel(const int* __restrict__ dst, int* __restrict__ counts, int E) {
    int e = blockIdx.x * blockDim.x + threadIdx.x;
    if (e < E) atomicAdd(&counts[dst[e]], 1);
}

#define SCAN_T 1024
__global__ __launch_bounds__(SCAN_T) void scan_kernel(const int* __restrict__ counts,
                                                      int* __restrict__ row_ofs, int Nn) {
    __shared__ int part[SCAN_T];
    int tid = threadIdx.x;
    int chunk = Nn / SCAN_T;
    int base = tid * chunk;
    int sum = 0;
    for (int i = 0; i < chunk; ++i) sum += counts[base + i];
    part[tid] = sum;
    __syncthreads();
    for (int off = 1; off < SCAN_T; off <<= 1) {
        int v = part[tid];
        int u = (tid >= off) ? part[tid - off] : 0;
        __syncthreads();
        part[tid] = v + u;
        __syncthreads();
    }
    if (tid == SCAN_T - 1) row_ofs[Nn] = part[tid];
    int acc = part[tid] - sum;  // exclusive prefix
    for (int i = 0; i < chunk; ++i) { row_ofs[base + i] = acc; acc += counts[base + i]; }
}

__global__ void scatter_kernel(const int* __restrict__ dst, const int* __restrict__ row_ofs,
                               int* __restrict__ cursor, int* __restrict__ perm, int E) {
    int e = blockIdx.x * blockDim.x + threadIdx.x;
    if (e < E) {
        int d = dst[e];
        int pos = atomicAdd(&cursor[d], 1);
        perm[row_ofs[d] + pos] = e;
    }
}

// ---------------- helpers ----------------
__device__ inline unsigned short bf16_bits(float f) {
    __hip_bfloat16 b = __float2bfloat16(f);
    return *reinterpret_cast<unsigned short*>(&b);
}
__device__ inline float bfu(unsigned short u) {
    return __uint_as_float(((unsigned)u) << 16);
}

// ---------------- fp32 -> bf16 bulk convert (x -> xb for gather halving) ----------------
__global__ void f32_to_bf16_kernel(const float4* __restrict__ in, ushort4* __restrict__ out, int n4) {
    int i = blockIdx.x * blockDim.x + threadIdx.x;
    if (i < n4) {
        float4 v = in[i];
        ushort4 o;
        o.x = bf16_bits(v.x); o.y = bf16_bits(v.y);
        o.z = bf16_bits(v.z); o.w = bf16_bits(v.w);
        out[i] = o;
    }
}

// ---------------- w_as/w_ad precompute ----------------
__global__ void wvec_kernel(const float* __restrict__ W, const float* __restrict__ a_s,
                            const float* __restrict__ a_d, float* __restrict__ w_as,
                            float* __restrict__ w_ad, int DIN, int H, int C) {
    int gid = blockIdx.x * blockDim.x + threadIdx.x;
    int wid = gid >> 6;
    int lane = threadIdx.x & 63;
    if (wid >= H * DIN) return;
    int h = wid / DIN, i = wid % DIN;
    const float* wp = W + (size_t)i * H * C + (size_t)h * C;
    const float* sp = a_s + (size_t)h * C;
    const float* dp = a_d + (size_t)h * C;
    float ss = 0.f, sd = 0.f;
    for (int c = lane; c < C; c += 64) {
        float v = wp[c];
        ss += v * sp[c];
        sd += v * dp[c];
    }
    #pragma unroll
    for (int off = 32; off > 0; off >>= 1) {
        ss += __shfl_down(ss, off, 64);
        sd += __shfl_down(sd, off, 64);
    }
    if (lane == 0) { w_as[wid] = ss; w_ad[wid] = sd; }
}

// ---------------- layer-1 alpha dots, w-vectors LDS-cached; one wave per node ----------------
__global__ __launch_bounds__(256) void alpha16_kernel(const float4* __restrict__ x4,
                                                      const float* __restrict__ wv,
                                                      float* __restrict__ as_out,
                                                      float* __restrict__ ad_out) {
    __shared__ float ws[16 * 768];
    int tid = threadIdx.x;
    #pragma unroll
    for (int i = 0; i < 12; ++i)
        ((float4*)ws)[tid + i * 256] = ((const float4*)wv)[tid + i * 256];
    __syncthreads();
    int wvid = tid >> 6, lane = tid & 63;
    int n = blockIdx.x * 4 + wvid;
    float4 xr[3];
    #pragma unroll
    for (int r = 0; r < 3; ++r) xr[r] = x4[(size_t)n * 192 + lane + 64 * r];
    #pragma unroll
    for (int j = 0; j < 16; ++j) {
        const float4* wj = (const float4*)(ws + j * 768);
        float s = 0.f;
        #pragma unroll
        for (int r = 0; r < 3; ++r) {
            float4 wc = wj[lane + 64 * r];
            s += xr[r].x * wc.x + xr[r].y * wc.y + xr[r].z * wc.z + xr[r].w * wc.w;
        }
        #pragma unroll
        for (int off = 32; off > 0; off >>= 1) s += __shfl_down(s, off, 64);
        if (lane == 0) {
            if (j < 8) as_out[n * 8 + j] = s;
            else       ad_out[n * 8 + (j - 8)] = s;
        }
    }
}

// ---------------- FUSED: per-node softmax (8 heads) + 8-head aggregation -> zAB bf16 ----------------
__global__ __launch_bounds__(192) void agg8_fused_kernel(
    const ushort4* __restrict__ xb4,  // [N][192] bf16 x (gather-halved)
    const float* __restrict__ as1,    // [N][8]
    const float* __restrict__ ad1,    // [N][8]
    const int* __restrict__ src,
    const int* __restrict__ row_ofs,
    const int* __restrict__ perm,
    float* __restrict__ e1g,          // [E][8] global fallback alpha
    __hip_bfloat16* __restrict__ zAB, // [N][8*768]
    int D4) {
    __shared__ float alds[MAXD * 8];
    __shared__ float mh[8], dh[8];
    int n = blockIdx.x;
    int s = row_ofs[n], t = row_ofs[n + 1];
    int d = t - s;
    int tid = threadIdx.x;
    bool big = d > MAXD;
    if (!big) {
        int eh = tid & 7, ei = tid >> 3;  // ei in 0..23
        float adn = ad1[n * 8 + eh];
        for (int base = 0; base < d; base += 24) {
            int j = base + ei;
            if (j < d) {
                int e = perm[s + j];
                float v = as1[src[e] * 8 + eh] + adn;
                v = v > 0.f ? v : 0.2f * v;
                alds[j * 8 + eh] = v;
            }
        }
        __syncthreads();
        if (tid < 8) {
            float m = -INFINITY;
            for (int j = 0; j < d; ++j) m = fmaxf(m, alds[j * 8 + tid]);
            float den = 0.f;
            for (int j = 0; j < d; ++j) den += __expf(alds[j * 8 + tid] - m);
            mh[tid] = m; dh[tid] = 1.f / (den + 1e-16f);
        }
        __syncthreads();
        for (int base = 0; base < d; base += 24) {
            int j = base + ei;
            if (j < d) alds[j * 8 + eh] = __expf(alds[j * 8 + eh] - mh[eh]) * dh[eh];
        }
        __syncthreads();
    } else {
        if (tid < 8) {
            int hh = tid;
            float adn = ad1[n * 8 + hh];
            float m = -INFINITY;
            for (int j = s; j < t; ++j) {
                float v = as1[src[perm[j]] * 8 + hh] + adn;
                v = v > 0.f ? v : 0.2f * v;
                m = fmaxf(m, v);
            }
            float den = 0.f;
            for (int j = s; j < t; ++j) {
                float v = as1[src[perm[j]] * 8 + hh] + adn;
                v = v > 0.f ? v : 0.2f * v;
                den += __expf(v - m);
            }
            float inv = 1.f / (den + 1e-16f);
            for (int j = s; j < t; ++j) {
                int e = perm[j];
                float v = as1[src[e] * 8 + hh] + adn;
                v = v > 0.f ? v : 0.2f * v;
                e1g[(size_t)e * 8 + hh] = __expf(v - m) * inv;
            }
        }
        __syncthreads();
    }

    // aggregation: thread j handles bf16x4 column j for all 8 heads
    int j = tid;
    float4 acc[8];
    #pragma unroll
    for (int h = 0; h < 8; ++h) acc[h] = make_float4(0.f, 0.f, 0.f, 0.f);
    int k = s;
    for (; k + 1 < t; k += 2) {
        int e0 = perm[k], e1 = perm[k + 1];
        ushort4 u0 = xb4[(size_t)src[e0] * D4 + j];
        ushort4 u1 = xb4[(size_t)src[e1] * D4 + j];
        float4 v0 = make_float4(bfu(u0.x), bfu(u0.y), bfu(u0.z), bfu(u0.w));
        float4 v1 = make_float4(bfu(u1.x), bfu(u1.y), bfu(u1.z), bfu(u1.w));
        const float* a0 = big ? &e1g[(size_t)e0 * 8] : &alds[(k - s) * 8];
        const float* a1 = big ? &e1g[(size_t)e1 * 8] : &alds[(k + 1 - s) * 8];
        #pragma unroll
        for (int h = 0; h < 8; ++h) {
            float a = a0[h], b = a1[h];
            acc[h].x += a * v0.x + b * v1.x;
            acc[h].y += a * v0.y + b * v1.y;
            acc[h].z += a * v0.z + b * v1.z;
            acc[h].w += a * v0.w + b * v1.w;
        }
    }
    if (k < t) {
        int e0 = perm[k];
        ushort4 u0 = xb4[(size_t)src[e0] * D4 + j];
        float4 v0 = make_float4(bfu(u0.x), bfu(u0.y), bfu(u0.z), bfu(u0.w));
        const float* a0 = big ? &e1g[(size_t)e0 * 8] : &alds[(k - s) * 8];
        #pragma unroll
        for (int h = 0; h < 8; ++h) {
            float a = a0[h];
            acc[h].x += a * v0.x; acc[h].y += a * v0.y;
            acc[h].z += a * v0.z; acc[h].w += a * v0.w;
        }
    }
    int D = D4 * 4;
    #pragma unroll
    for (int h = 0; h < 8; ++h) {
        size_t o = (size_t)n * 8 * D + (size_t)h * D + j * 4;
        ushort4 st;
        st.x = bf16_bits(acc[h].x); st.y = bf16_bits(acc[h].y);
        st.z = bf16_bits(acc[h].z); st.w = bf16_bits(acc[h].w);
        *reinterpret_cast<ushort4*>(&zAB[o]) = st;
    }
}

// ---------------- FUSED: layer-2 softmax (H=1) + output aggregation (+bias) ----------------
__global__ __launch_bounds__(192) void out_fused_kernel(
    const ushort4* __restrict__ featb,  // h2b [N][192] bf16 (gather-halved)
    const float* __restrict__ as2,      // [N]
    const float* __restrict__ ad2,      // [N]
    const int* __restrict__ src,
    const int* __restrict__ row_ofs,
    const int* __restrict__ perm,
    float* __restrict__ e2g,            // [E] global fallback alpha
    const float4* __restrict__ bias4,
    float4* __restrict__ out4, int D4) {
    __shared__ float alds[MAXD];
    __shared__ float minv[2];
    int n = blockIdx.x;
    int s = row_ofs[n], t = row_ofs[n + 1];
    int d = t - s;
    int tid = threadIdx.x;
    bool big = d > MAXD;
    if (!big) {
        float adn = ad2[n];
        if (tid < d) {
            float v = as2[src[perm[s + tid]]] + adn;
            v = v > 0.f ? v : 0.2f * v;
            alds[tid] = v;
        }
        __syncthreads();
        if (tid == 0) {
            float m = -INFINITY;
            for (int j = 0; j < d; ++j) m = fmaxf(m, alds[j]);
            float den = 0.f;
            for (int j = 0; j < d; ++j) den += __expf(alds[j] - m);
            minv[0] = m; minv[1] = 1.f / (den + 1e-16f);
        }
        __syncthreads();
        if (tid < d) alds[tid] = __expf(alds[tid] - minv[0]) * minv[1];
        __syncthreads();
    } else {
        if (tid == 0) {
            float adn = ad2[n];
            float m = -INFINITY;
            for (int j = s; j < t; ++j) {
                float v = as2[src[perm[j]]] + adn;
                v = v > 0.f ? v : 0.2f * v;
                m = fmaxf(m, v);
            }
            float den = 0.f;
            for (int j = s; j < t; ++j) {
                float v = as2[src[perm[j]]] + adn;
                v = v > 0.f ? v : 0.2f * v;
                den += __expf(v - m);
            }
            float inv = 1.f / (den + 1e-16f);
            for (int j = s; j < t; ++j) {
                int e = perm[j];
                float v = as2[src[e]] + adn;
                v = v > 0.f ? v : 0.2f * v;
                e2g[e] = __expf(v - m) * inv;
            }
        }
        __syncthreads();
    }

    int j = tid;
    float4 acc = make_float4(0.f, 0.f, 0.f, 0.f);
    int k = s;
    for (; k + 1 < t; k += 2) {
        int e0 = perm[k], e1 = perm[k + 1];
        float a = big ? e2g[e0] : alds[k - s];
        float b = big ? e2g[e1] : alds[k + 1 - s];
        ushort4 u0 = featb[(size_t)src[e0] * D4 + j];
        ushort4 u1 = featb[(size_t)src[e1] * D4 + j];
        acc.x += a * bfu(u0.x) + b * bfu(u1.x);
        acc.y += a * bfu(u0.y) + b * bfu(u1.y);
        acc.z += a * bfu(u0.z) + b * bfu(u1.z);
        acc.w += a * bfu(u0.w) + b * bfu(u1.w);
    }
    if (k < t) {
        int e0 = perm[k];
        float a = big ? e2g[e0] : alds[k - s];
        ushort4 u0 = featb[(size_t)src[e0] * D4 + j];
        acc.x += a * bfu(u0.x); acc.y += a * bfu(u0.y);
        acc.z += a * bfu(u0.z); acc.w += a * bfu(u0.w);
    }
    float4 b = bias4[j];
    acc.x += b.x; acc.y += b.y; acc.z += b.z; acc.w += b.w;
    out4[(size_t)n * D4 + j] = acc;
}

// ---------------- transpose + fp32->bf16 ----------------
__global__ void transpose_bf16_kernel(const float* __restrict__ src, __hip_bfloat16* __restrict__ dst,
                                      int R, int Cc) {
    __shared__ float tile[32][33];
    int bx = blockIdx.x * 32;
    int by = blockIdx.y * 32;
    int tx = threadIdx.x, ty = threadIdx.y;  // 32 x 8
    #pragma unroll
    for (int i = 0; i < 32; i += 8)
        tile[ty + i][tx] = src[(size_t)(by + ty + i) * Cc + (bx + tx)];
    __syncthreads();
    #pragma unroll
    for (int i = 0; i < 32; i += 8)
        dst[(size_t)(bx + ty + i) * R + (by + tx)] = __float2bfloat16(tile[tx][ty + i]);
}

// ---------------- fused: h2 = p0+p1 (split-K S=2) -> bf16; as2/ad2 = h2 . a_s2 / a_d2 ----------------
__global__ __launch_bounds__(192) void reduce_dot_kernel(
    const float4* __restrict__ parts,  // [2][N][192]
    const float4* __restrict__ as_w, const float4* __restrict__ ad_w,
    ushort4* __restrict__ h2b,         // [N][192] bf16 out
    float* __restrict__ as_out, float* __restrict__ ad_out, int NC4) {
    int n = blockIdx.x;
    int j = threadIdx.x;
    size_t idx = (size_t)n * 192 + j;
    float4 a = parts[idx];
    float4 p1 = parts[(size_t)NC4 + idx];
    a.x += p1.x; a.y += p1.y; a.z += p1.z; a.w += p1.w;
    ushort4 st;
    st.x = bf16_bits(a.x); st.y = bf16_bits(a.y);
    st.z = bf16_bits(a.z); st.w = bf16_bits(a.w);
    h2b[idx] = st;
    float4 ws = as_w[j], wd = ad_w[j];
    float ss = a.x * ws.x + a.y * ws.y + a.z * ws.z + a.w * ws.w;
    float sd = a.x * wd.x + a.y * wd.y + a.z * wd.z + a.w * wd.w;
    #pragma unroll
    for (int off = 32; off > 0; off >>= 1) {
        ss += __shfl_down(ss, off, 64);
        sd += __shfl_down(sd, off, 64);
    }
    __shared__ float red_s[3], red_d[3];
    int wv = j >> 6, lane = j & 63;
    if (lane == 0) { red_s[wv] = ss; red_d[wv] = sd; }
    __syncthreads();
    if (j == 0) {
        as_out[n] = red_s[0] + red_s[1] + red_s[2];
        ad_out[n] = red_d[0] + red_d[1] + red_d[2];
    }
}

// ---------------- bf16 MFMA GEMM, 256x256 tile, pipelined 8-phase counted-vmcnt schedule ----------------
// C[M,N] = A[M,K] @ BT[N,K]^T.  BM=BN=256, BK=64, 512 threads (8 waves, 2Mx4N),
// 128 KiB double-buffered LDS, XOR bank-swizzle on pre-swizzled global source + ds_read.
// Cross-phase fragment pipelining: each tile's full fragment set (24 ds_read_b128) is
// issued into the ALTERNATE register set right after the buffer-ready vmcnt+barrier,
// overlapping the previous tile's last MFMA cluster. 2 barriers/K-tile:
//   BAR-A (lgkm drain: all tile reads done -> stages into that buf may begin)
//   BAR-B (vmcnt(4): next buf fully landed -> reads may begin)
// Tail iteration uses vmcnt(0) (fixes latent last-tile race). setprio around MFMA,
// XCD swizzle (grid%8==0).
__device__ inline void gload_lds16(const void* g, void* l) {
    __builtin_amdgcn_global_load_lds((const __attribute__((address_space(1))) unsigned int*)g,
                                     (__attribute__((address_space(3))) unsigned int*)l, 16, 0, 0);
}

#define FENCE() asm volatile("" ::: "memory")
#define BAR() do { FENCE(); __builtin_amdgcn_s_barrier(); FENCE(); } while (0)
#define WAIT_LGKM() asm volatile("s_waitcnt lgkmcnt(0)" ::: "memory")
#define WAIT_VM4() asm volatile("s_waitcnt vmcnt(4)" ::: "memory")
#define WAIT_VM6() asm volatile("s_waitcnt vmcnt(6)" ::: "memory")
#define WAIT_VM0() asm volatile("s_waitcnt vmcnt(0)" ::: "memory")
#define SCHED0() __builtin_amdgcn_sched_barrier(0)

// stage half h (128 rows) of K-tile kt into buffer b (2 x global_load_lds, 16B/lane)
#define STAGE_A(b, h, kt) do { \
    const __hip_bfloat16* _s = gA0 + (size_t)(h) * 2 * lstrA + (size_t)(kt) * 64; \
    short* _d = dA + (b) * 16384 + (h) * 8192; \
    gload_lds16(_s, _d); \
    gload_lds16(_s + lstrA, _d + 4096); \
} while (0)

#define STAGE_B(b, h, kt) do { \
    const __hip_bfloat16* _s = gB0 + (size_t)(h) * 2 * lstrB + (size_t)(kt) * 64; \
    short* _d = dB + (b) * 16384 + (h) * 8192; \
    gload_lds16(_s, _d); \
    gload_lds16(_s + lstrB, _d + 4096); \
} while (0)

// load ALL B fragments (both NQ) for buffer b into register set dst (8 x ds_read_b128)
#define LOAD_BF(dst, b) do { \
    _Pragma("unroll") for (int nq = 0; nq < 2; ++nq) \
    _Pragma("unroll") for (int ni = 0; ni < 2; ++ni) { \
        const short* _p = Bsb + (b) * 16384 + brb + nq * (128 * 64) + ni * (16 * 64); \
        dst[nq][ni][0] = *(const s16x8*)(_p + csw0); \
        dst[nq][ni][1] = *(const s16x8*)(_p + csw1); \
    } \
} while (0)

// load ALL A fragments (both MQ) for buffer b into register set dst (16 x ds_read_b128)
#define LOAD_AF(dst, b) do { \
    _Pragma("unroll") for (int mq = 0; mq < 2; ++mq) \
    _Pragma("unroll") for (int mi = 0; mi < 4; ++mi) { \
        const short* _p = Asb + (b) * 16384 + arb + mq * (128 * 64) + mi * (16 * 64); \
        dst[mq][mi][0] = *(const s16x8*)(_p + csw0); \
        dst[mq][mi][1] = *(const s16x8*)(_p + csw1); \
    } \
} while (0)

#define MMAC(afs, bfs, MQ, NQ) do { \
    __builtin_amdgcn_s_setprio(1); \
    _Pragma("unroll") for (int ks = 0; ks < 2; ++ks) \
        _Pragma("unroll") for (int mi = 0; mi < 4; ++mi) \
            _Pragma("unroll") for (int ni = 0; ni < 2; ++ni) \
                acc[MQ][NQ][mi][ni] = __builtin_amdgcn_mfma_f32_16x16x32_bf16( \
                    afs[MQ][mi][ks], bfs[NQ][ni][ks], acc[MQ][NQ][mi][ni], 0, 0, 0); \
    __builtin_amdgcn_s_setprio(0); \
} while (0)

__global__ __launch_bounds__(512, 2) void gemm256_kernel(
    const __hip_bfloat16* __restrict__ A,   // [M][lda]
    const __hip_bfloat16* __restrict__ BT,  // [N][ldb]
    int lda, int ldb, int ldc,
    int K, int kofs_per_z,
    const float* __restrict__ bias,
    __hip_bfloat16* __restrict__ Cb,        // bf16 out or null
    float* __restrict__ Cf,                 // fp32 out (used if Cb==null)
    int flags,                              // 1 = elu
    long bsA, long bsBT, long bsC, long bsBias,
    int GX, int GY) {
    extern __shared__ __align__(16) short lds[];
    short* Asb = lds;            // [2][256][64] = 32768 shorts = 64 KiB
    short* Bsb = lds + 32768;    // [2][256][64]

    int lin = blockIdx.x;
    int xcd = lin & 7;
    int u = lin >> 3;
    int bx = u % GX;
    int cg = u / GX;
    int cc = cg * 8 + xcd;
    int by = cc % GY;
    int bz = cc / GY;

    int kofs = bz * kofs_per_z;
    A += (size_t)bz * bsA;
    BT += (size_t)bz * bsBT;
    if (Cb) Cb += (size_t)bz * bsC;
    else    Cf += (size_t)bz * bsC;
    if (bias) bias += (size_t)bz * bsBias;

    int tid = threadIdx.x;
    int lane = tid & 63;
    int wid = tid >> 6;
    int wm = wid >> 2;      // 0..1
    int wn = wid & 3;       // 0..3
    int ml = lane & 15;
    int g  = lane >> 4;     // 0..3

    int row0 = by * 256;
    int col0 = bx * 256;

    // --- staging addresses (pre-swizzled global source, linear LDS dest) ---
    int sr = tid >> 3;                  // row 0..63 within 64-row quarter
    int scl = (tid & 7) ^ (sr & 7);     // swizzled logical 16B-chunk
    const __hip_bfloat16* gA0 = A + (size_t)(row0 + sr) * lda + kofs + scl * 8;
    const __hip_bfloat16* gB0 = BT + (size_t)(col0 + sr) * ldb + kofs + scl * 8;
    size_t lstrA = (size_t)64 * lda;
    size_t lstrB = (size_t)64 * ldb;
    short* dA = Asb + tid * 8;
    short* dB = Bsb + tid * 8;

    // --- fragment read addressing (swizzled chunk = logical ^ (row&7)) ---
    int arb = (wm * 64 + ml) * 64;      // A row base (shorts)
    int brb = (wn * 32 + ml) * 64;      // B row base (shorts)
    int csw0 = ((g) ^ (ml & 7)) * 8;        // ks=0 chunk offset (shorts)
    int csw1 = ((4 + g) ^ (ml & 7)) * 8;    // ks=1

    f32x4 acc[2][2][4][2];
    #pragma unroll
    for (int a0 = 0; a0 < 2; ++a0)
    #pragma unroll
    for (int b0 = 0; b0 < 2; ++b0)
    #pragma unroll
    for (int c0 = 0; c0 < 4; ++c0)
    #pragma unroll
    for (int d0 = 0; d0 < 2; ++d0) acc[a0][b0][c0][d0] = (f32x4){0.f, 0.f, 0.f, 0.f};

    // two fragment register sets: set0 for even tiles (buf0), set1 for odd (buf1)
    s16x8 af0[2][4][2], af1[2][4][2];
    s16x8 bf0[2][2][2], bf1[2][2][2];

    int nkt = K / 64;

    // prologue: tile0 full (buf0) + tile1 A0,B0,A1 (buf1) = 14 loads
    STAGE_A(0, 0, 0); STAGE_B(0, 0, 0); STAGE_A(0, 1, 0); STAGE_B(0, 1, 0);
    STAGE_A(1, 0, 1); STAGE_B(1, 0, 1); STAGE_A(1, 1, 1);
    WAIT_VM6();   // tile0's 8 loads landed
    BAR();
    LOAD_BF(bf0, 0); LOAD_AF(af0, 0);
    SCHED0();

    for (int i = 0; i < nkt / 2; ++i) {
        int t1 = 2 * i + 1, t2 = 2 * i + 2, t3 = 2 * i + 3;
        bool pf = t2 < nkt;  // even nkt: p2 == p3
        // P1: tile 2i (0,0)
        STAGE_B(1, 1, t1);
        MMAC(af0, bf0, 0, 0);
        WAIT_LGKM(); BAR();          // BAR-A: all buf0 reads drained -> buf0 stages ok
        // P2: (0,1)
        if (pf) STAGE_A(0, 0, t2);
        MMAC(af0, bf0, 0, 1);
        // P3: (1,0)
        if (pf) STAGE_B(0, 0, t2);
        MMAC(af0, bf0, 1, 0);
        if (pf) { WAIT_VM4(); } else { WAIT_VM0(); }
        BAR();                        // BAR-B: buf1 (tile 2i+1) fully landed
        // P4: (1,1) + prefetch ALL of tile 2i+1's fragments into set1
        LOAD_BF(bf1, 1); LOAD_AF(af1, 1);
        SCHED0();
        if (pf) STAGE_A(0, 1, t2);
        MMAC(af0, bf0, 1, 1);
        // P5: tile 2i+1 (0,0)
        if (pf) STAGE_B(0, 1, t2);
        MMAC(af1, bf1, 0, 0);
        WAIT_LGKM(); BAR();          // BAR-C: all buf1 reads drained -> buf1 stages ok
        // P6: (0,1)
        if (pf) STAGE_A(1, 0, t3);
        MMAC(af1, bf1, 0, 1);
        // P7: (1,0)
        if (pf) STAGE_B(1, 0, t3);
        MMAC(af1, bf1, 1, 0);
        if (pf) { WAIT_VM4(); } else { WAIT_VM0(); }
        BAR();                        // BAR-D: buf0 (tile 2i+2) fully landed
        // P8: (1,1) + prefetch next tile's fragments into set0
        if (pf) { LOAD_BF(bf0, 0); LOAD_AF(af0, 0); SCHED0(); }
        if (pf) STAGE_A(1, 1, t3);
        MMAC(af1, bf1, 1, 1);
    }

    // epilogue: C/D mapping col=lane&15, row=(lane>>4)*4+r (verified layout)
    #pragma unroll
    for (int mq = 0; mq < 2; ++mq)
    #pragma unroll
    for (int nq = 0; nq < 2; ++nq)
    #pragma unroll
    for (int mi = 0; mi < 4; ++mi)
    #pragma unroll
    for (int ni = 0; ni < 2; ++ni) {
        int row = row0 + mq * 128 + wm * 64 + mi * 16 + g * 4;
        int col = col0 + nq * 128 + wn * 32 + ni * 16 + ml;
        float bv = bias ? bias[col] : 0.f;
        #pragma unroll
        for (int r = 0; r < 4; ++r) {
            float v = acc[mq][nq][mi][ni][r] + bv;
            if (flags & 1) {
                float ev = __expf(v) - 1.f;  // elu (select, no branch)
                v = v > 0.f ? v : ev;
            }
            size_t idx = (size_t)(row + r) * ldc + col;
            if (Cb) Cb[idx] = __float2bfloat16(v);
            else    Cf[idx] = v;
        }
    }
}

// ---------------- launch ----------------
extern "C" void kernel_launch(void* const* d_in, const int* in_sizes, int n_in,
                              void* d_out, int out_size, void* d_ws, size_t ws_size,
                              hipStream_t stream) {
    const int N = 8192, E = 65536, DIN = 768, C = 768, H1n = 8;
    const int HC1 = H1n * C;  // 6144

    const float* x    = (const float*)d_in[0];
    const float* W1   = (const float*)d_in[1];
    const float* a_s1 = (const float*)d_in[2];
    const float* a_d1 = (const float*)d_in[3];
    const float* b1   = (const float*)d_in[4];
    const float* W2   = (const float*)d_in[5];
    const float* a_s2 = (const float*)d_in[6];
    const float* a_d2 = (const float*)d_in[7];
    const float* b2   = (const float*)d_in[8];
    const int*   edges = (const int*)d_in[9];
    const int* src = edges;
    const int* dst = edges + E;

    // ---- workspace layout (~248.7 MB) ----
    char* w = (char*)d_ws;
    auto alloc = [&](size_t bytes) -> void* {
        void* p = (void*)w;
        w += (bytes + 255) & ~(size_t)255;
        return p;
    };
    __hip_bfloat16* zAB = (__hip_bfloat16*)alloc((size_t)N * HC1 * 2);      // 100.7 MB
    __hip_bfloat16* o1  = (__hip_bfloat16*)alloc((size_t)N * HC1 * 2);      // 100.7 MB
    ushort4* xb4        = (ushort4*)alloc((size_t)N * DIN * 2);             // 12.6 MB
    ushort4* h2b        = (ushort4*)alloc((size_t)N * C * 2);               // 12.6 MB
    __hip_bfloat16* W1T = (__hip_bfloat16*)alloc((size_t)HC1 * DIN * 2);    // 9.4 MB
    __hip_bfloat16* W2T = (__hip_bfloat16*)alloc((size_t)C * HC1 * 2);      // 9.4 MB
    float* wv      = (float*)alloc((size_t)16 * DIN * 4);
    float* as1     = (float*)alloc((size_t)N * H1n * 4);
    float* ad1     = (float*)alloc((size_t)N * H1n * 4);
    float* e1      = (float*)alloc((size_t)E * H1n * 4);   // fallback alpha (deg > MAXD)
    float* as2     = (float*)alloc((size_t)N * 4);
    float* ad2     = (float*)alloc((size_t)N * 4);
    float* e2      = (float*)alloc((size_t)E * 4);         // fallback alpha (deg > MAXD)
    int*   counts  = (int*)alloc((size_t)N * 4);
    int*   cursor  = (int*)alloc((size_t)N * 4);
    int*   row_ofs = (int*)alloc((size_t)(N + 1) * 4);
    int*   perm    = (int*)alloc((size_t)E * 4);

    // split-K partials for GEMM2 (S=2) alias zAB (dead after GEMM1; 2*25.2 <= 100.7 MB)
    float* partials = (float*)zAB;

    // 128 KiB dynamic LDS for the 256^2 GEMM
    (void)hipFuncSetAttribute((const void*)gemm256_kernel,
                              hipFuncAttributeMaxDynamicSharedMemorySize, 131072);

    // ---- CSR by dst ----
    zero2_kernel<<<(N + 255) / 256, 256, 0, stream>>>(counts, cursor, N);
    hist_kernel<<<(E + 255) / 256, 256, 0, stream>>>(dst, counts, E);
    scan_kernel<<<1, SCAN_T, 0, stream>>>(counts, row_ofs, N);
    scatter_kernel<<<(E + 255) / 256, 256, 0, stream>>>(dst, row_ofs, cursor, perm, E);

    // ---- x -> bf16 gather table ----
    {
        int n4 = N * DIN / 4;
        f32_to_bf16_kernel<<<(n4 + 255) / 256, 256, 0, stream>>>((const float4*)x, xb4, n4);
    }

    // ---- weight transforms (bf16, transposed) ----
    {
        dim3 b(32, 8);
        dim3 g1(HC1 / 32, DIN / 32);
        transpose_bf16_kernel<<<g1, b, 0, stream>>>(W1, W1T, DIN, HC1);
        dim3 g2(C / 32, HC1 / 32);
        transpose_bf16_kernel<<<g2, b, 0, stream>>>(W2, W2T, HC1, C);
    }

    // ---- Layer 1 attention coefficients ----
    wvec_kernel<<<(H1n * DIN * 64 + 255) / 256, 256, 0, stream>>>(W1, a_s1, a_d1, wv, wv + 8 * DIN, DIN, H1n, C);
    alpha16_kernel<<<N / 4, 256, 0, stream>>>((const float4*)x, wv, as1, ad1);

    // ---- fused softmax + 8-head aggregation: xb -> zAB (bf16) ----
    agg8_fused_kernel<<<N, 192, 0, stream>>>(xb4, as1, ad1, src, row_ofs, perm,
                                             e1, zAB, DIN / 4);

    // ---- GEMM1: all 8 heads; o1 = ELU(z @ W1 + b1) ----
    {
        int GX = C / 256, GY = N / 256;  // 3 x 32 x 8 heads = 768 blocks
        gemm256_kernel<<<GX * GY * H1n, 512, 131072, stream>>>(
            zAB, W1T,
            HC1, DIN, HC1,
            DIN, /*kofs_per_z=*/0,
            b1, o1, nullptr, /*flags=*/1,
            /*bsA=*/C, /*bsBT=*/(long)C * DIN, /*bsC=*/C, /*bsBias=*/C,
            GX, GY);
    }
    // ---- GEMM2: K=6144 split-K S=2 into partials (aliasing zAB) ----
    {
        int GX = C / 256, GY = N / 256;  // 3 x 32 x 2 = 192 blocks
        int Kslice = HC1 / 2;            // 3072 -> 48 K-tiles/block
        gemm256_kernel<<<GX * GY * 2, 512, 131072, stream>>>(
            o1, W2T,
            HC1, HC1, C,
            Kslice, /*kofs_per_z=*/Kslice,
            nullptr, nullptr, partials, /*flags=*/0,
            0, 0, /*bsC=*/(long)N * C, 0,
            GX, GY);
    }

    // ---- fused: h2b = bf16(p0 + p1) ; as2/ad2 = h2 . a_s2 / a_d2 ----
    reduce_dot_kernel<<<N, 192, 0, stream>>>((const float4*)partials, (const float4*)a_s2,
                                             (const float4*)a_d2, h2b, as2, ad2, N * C / 4);

    // ---- fused layer-2 softmax + output aggregation ----
    out_fused_kernel<<<N, 192, 0, stream>>>(h2b, as2, ad2, src, row_ofs, perm,
                                            e2, (const float4*)b2, (float4*)d_out, C / 4);
}

// Round 4
// 442.908 us; speedup vs baseline: 3.3614x; 3.3614x over previous
//
#include <hip/hip_runtime.h>
#include <hip/hip_bf16.h>
#include <math.h>

typedef __attribute__((ext_vector_type(4))) float f32x4;
typedef __attribute__((ext_vector_type(8))) short s16x8;

#define MAXD 192  // fast-path degree cap for fused softmax (LDS alpha buffer)

// ---------------- CSR-by-dst construction ----------------

__global__ void zero2_kernel(int* __restrict__ a, int* __restrict__ b, int n) {
    int i = blockIdx.x * blockDim.x + threadIdx.x;
    if (i < n) { a[i] = 0; b[i] = 0; }
}

__global__ void hist_kernel(const int* __restrict__ dst, int* __restrict__ counts, int E) {
    int e = blockIdx.x * blockDim.x + threadIdx.x;
    if (e < E) atomicAdd(&counts[dst[e]], 1);
}

#define SCAN_T 1024
__global__ __launch_bounds__(SCAN_T) void scan_kernel(const int* __restrict__ counts,
                                                      int* __restrict__ row_ofs, int Nn) {
    __shared__ int part[SCAN_T];
    int tid = threadIdx.x;
    int chunk = Nn / SCAN_T;
    int base = tid * chunk;
    int sum = 0;
    for (int i = 0; i < chunk; ++i) sum += counts[base + i];
    part[tid] = sum;
    __syncthreads();
    for (int off = 1; off < SCAN_T; off <<= 1) {
        int v = part[tid];
        int u = (tid >= off) ? part[tid - off] : 0;
        __syncthreads();
        part[tid] = v + u;
        __syncthreads();
    }
    if (tid == SCAN_T - 1) row_ofs[Nn] = part[tid];
    int acc = part[tid] - sum;  // exclusive prefix
    for (int i = 0; i < chunk; ++i) { row_ofs[base + i] = acc; acc += counts[base + i]; }
}

__global__ void scatter_kernel(const int* __restrict__ dst, const int* __restrict__ row_ofs,
                               int* __restrict__ cursor, int* __restrict__ perm, int E) {
    int e = blockIdx.x * blockDim.x + threadIdx.x;
    if (e < E) {
        int d = dst[e];
        int pos = atomicAdd(&cursor[d], 1);
        perm[row_ofs[d] + pos] = e;
    }
}

// ---------------- helpers ----------------
__device__ inline unsigned short bf16_bits(float f) {
    __hip_bfloat16 b = __float2bfloat16(f);
    return *reinterpret_cast<unsigned short*>(&b);
}
__device__ inline float bfu(unsigned short u) {
    return __uint_as_float(((unsigned)u) << 16);
}

// ---------------- fp32 -> bf16 bulk convert (x -> xb for gather halving) ----------------
__global__ void f32_to_bf16_kernel(const float4* __restrict__ in, ushort4* __restrict__ out, int n4) {
    int i = blockIdx.x * blockDim.x + threadIdx.x;
    if (i < n4) {
        float4 v = in[i];
        ushort4 o;
        o.x = bf16_bits(v.x); o.y = bf16_bits(v.y);
        o.z = bf16_bits(v.z); o.w = bf16_bits(v.w);
        out[i] = o;
    }
}

// ---------------- w_as/w_ad precompute ----------------
__global__ void wvec_kernel(const float* __restrict__ W, const float* __restrict__ a_s,
                            const float* __restrict__ a_d, float* __restrict__ w_as,
                            float* __restrict__ w_ad, int DIN, int H, int C) {
    int gid = blockIdx.x * blockDim.x + threadIdx.x;
    int wid = gid >> 6;
    int lane = threadIdx.x & 63;
    if (wid >= H * DIN) return;
    int h = wid / DIN, i = wid % DIN;
    const float* wp = W + (size_t)i * H * C + (size_t)h * C;
    const float* sp = a_s + (size_t)h * C;
    const float* dp = a_d + (size_t)h * C;
    float ss = 0.f, sd = 0.f;
    for (int c = lane; c < C; c += 64) {
        float v = wp[c];
        ss += v * sp[c];
        sd += v * dp[c];
    }
    #pragma unroll
    for (int off = 32; off > 0; off >>= 1) {
        ss += __shfl_down(ss, off, 64);
        sd += __shfl_down(sd, off, 64);
    }
    if (lane == 0) { w_as[wid] = ss; w_ad[wid] = sd; }
}

// ---------------- layer-1 alpha dots, w-vectors LDS-cached; one wave per node ----------------
__global__ __launch_bounds__(256) void alpha16_kernel(const float4* __restrict__ x4,
                                                      const float* __restrict__ wv,
                                                      float* __restrict__ as_out,
                                                      float* __restrict__ ad_out) {
    __shared__ float ws[16 * 768];
    int tid = threadIdx.x;
    #pragma unroll
    for (int i = 0; i < 12; ++i)
        ((float4*)ws)[tid + i * 256] = ((const float4*)wv)[tid + i * 256];
    __syncthreads();
    int wvid = tid >> 6, lane = tid & 63;
    int n = blockIdx.x * 4 + wvid;
    float4 xr[3];
    #pragma unroll
    for (int r = 0; r < 3; ++r) xr[r] = x4[(size_t)n * 192 + lane + 64 * r];
    #pragma unroll
    for (int j = 0; j < 16; ++j) {
        const float4* wj = (const float4*)(ws + j * 768);
        float s = 0.f;
        #pragma unroll
        for (int r = 0; r < 3; ++r) {
            float4 wc = wj[lane + 64 * r];
            s += xr[r].x * wc.x + xr[r].y * wc.y + xr[r].z * wc.z + xr[r].w * wc.w;
        }
        #pragma unroll
        for (int off = 32; off > 0; off >>= 1) s += __shfl_down(s, off, 64);
        if (lane == 0) {
            if (j < 8) as_out[n * 8 + j] = s;
            else       ad_out[n * 8 + (j - 8)] = s;
        }
    }
}

// ---------------- FUSED: per-node softmax (8 heads) + 8-head aggregation -> zAB bf16 ----------------
__global__ __launch_bounds__(192) void agg8_fused_kernel(
    const ushort4* __restrict__ xb4,  // [N][192] bf16 x (gather-halved)
    const float* __restrict__ as1,    // [N][8]
    const float* __restrict__ ad1,    // [N][8]
    const int* __restrict__ src,
    const int* __restrict__ row_ofs,
    const int* __restrict__ perm,
    float* __restrict__ e1g,          // [E][8] global fallback alpha
    __hip_bfloat16* __restrict__ zAB, // [N][8*768]
    int D4) {
    __shared__ float alds[MAXD * 8];
    __shared__ float mh[8], dh[8];
    int n = blockIdx.x;
    int s = row_ofs[n], t = row_ofs[n + 1];
    int d = t - s;
    int tid = threadIdx.x;
    bool big = d > MAXD;
    if (!big) {
        int eh = tid & 7, ei = tid >> 3;  // ei in 0..23
        float adn = ad1[n * 8 + eh];
        for (int base = 0; base < d; base += 24) {
            int j = base + ei;
            if (j < d) {
                int e = perm[s + j];
                float v = as1[src[e] * 8 + eh] + adn;
                v = v > 0.f ? v : 0.2f * v;
                alds[j * 8 + eh] = v;
            }
        }
        __syncthreads();
        if (tid < 8) {
            float m = -INFINITY;
            for (int j = 0; j < d; ++j) m = fmaxf(m, alds[j * 8 + tid]);
            float den = 0.f;
            for (int j = 0; j < d; ++j) den += __expf(alds[j * 8 + tid] - m);
            mh[tid] = m; dh[tid] = 1.f / (den + 1e-16f);
        }
        __syncthreads();
        for (int base = 0; base < d; base += 24) {
            int j = base + ei;
            if (j < d) alds[j * 8 + eh] = __expf(alds[j * 8 + eh] - mh[eh]) * dh[eh];
        }
        __syncthreads();
    } else {
        if (tid < 8) {
            int hh = tid;
            float adn = ad1[n * 8 + hh];
            float m = -INFINITY;
            for (int j = s; j < t; ++j) {
                float v = as1[src[perm[j]] * 8 + hh] + adn;
                v = v > 0.f ? v : 0.2f * v;
                m = fmaxf(m, v);
            }
            float den = 0.f;
            for (int j = s; j < t; ++j) {
                float v = as1[src[perm[j]] * 8 + hh] + adn;
                v = v > 0.f ? v : 0.2f * v;
                den += __expf(v - m);
            }
            float inv = 1.f / (den + 1e-16f);
            for (int j = s; j < t; ++j) {
                int e = perm[j];
                float v = as1[src[e] * 8 + hh] + adn;
                v = v > 0.f ? v : 0.2f * v;
                e1g[(size_t)e * 8 + hh] = __expf(v - m) * inv;
            }
        }
        __syncthreads();
    }

    // aggregation: thread j handles bf16x4 column j for all 8 heads
    int j = tid;
    float4 acc[8];
    #pragma unroll
    for (int h = 0; h < 8; ++h) acc[h] = make_float4(0.f, 0.f, 0.f, 0.f);
    int k = s;
    for (; k + 1 < t; k += 2) {
        int e0 = perm[k], e1 = perm[k + 1];
        ushort4 u0 = xb4[(size_t)src[e0] * D4 + j];
        ushort4 u1 = xb4[(size_t)src[e1] * D4 + j];
        float4 v0 = make_float4(bfu(u0.x), bfu(u0.y), bfu(u0.z), bfu(u0.w));
        float4 v1 = make_float4(bfu(u1.x), bfu(u1.y), bfu(u1.z), bfu(u1.w));
        const float* a0 = big ? &e1g[(size_t)e0 * 8] : &alds[(k - s) * 8];
        const float* a1 = big ? &e1g[(size_t)e1 * 8] : &alds[(k + 1 - s) * 8];
        #pragma unroll
        for (int h = 0; h < 8; ++h) {
            float a = a0[h], b = a1[h];
            acc[h].x += a * v0.x + b * v1.x;
            acc[h].y += a * v0.y + b * v1.y;
            acc[h].z += a * v0.z + b * v1.z;
            acc[h].w += a * v0.w + b * v1.w;
        }
    }
    if (k < t) {
        int e0 = perm[k];
        ushort4 u0 = xb4[(size_t)src[e0] * D4 + j];
        float4 v0 = make_float4(bfu(u0.x), bfu(u0.y), bfu(u0.z), bfu(u0.w));
        const float* a0 = big ? &e1g[(size_t)e0 * 8] : &alds[(k - s) * 8];
        #pragma unroll
        for (int h = 0; h < 8; ++h) {
            float a = a0[h];
            acc[h].x += a * v0.x; acc[h].y += a * v0.y;
            acc[h].z += a * v0.z; acc[h].w += a * v0.w;
        }
    }
    int D = D4 * 4;
    #pragma unroll
    for (int h = 0; h < 8; ++h) {
        size_t o = (size_t)n * 8 * D + (size_t)h * D + j * 4;
        ushort4 st;
        st.x = bf16_bits(acc[h].x); st.y = bf16_bits(acc[h].y);
        st.z = bf16_bits(acc[h].z); st.w = bf16_bits(acc[h].w);
        *reinterpret_cast<ushort4*>(&zAB[o]) = st;
    }
}

// ---------------- FUSED: layer-2 softmax (H=1) + output aggregation (+bias) ----------------
__global__ __launch_bounds__(192) void out_fused_kernel(
    const ushort4* __restrict__ featb,  // h2b [N][192] bf16 (gather-halved)
    const float* __restrict__ as2,      // [N]
    const float* __restrict__ ad2,      // [N]
    const int* __restrict__ src,
    const int* __restrict__ row_ofs,
    const int* __restrict__ perm,
    float* __restrict__ e2g,            // [E] global fallback alpha
    const float4* __restrict__ bias4,
    float4* __restrict__ out4, int D4) {
    __shared__ float alds[MAXD];
    __shared__ float minv[2];
    int n = blockIdx.x;
    int s = row_ofs[n], t = row_ofs[n + 1];
    int d = t - s;
    int tid = threadIdx.x;
    bool big = d > MAXD;
    if (!big) {
        float adn = ad2[n];
        if (tid < d) {
            float v = as2[src[perm[s + tid]]] + adn;
            v = v > 0.f ? v : 0.2f * v;
            alds[tid] = v;
        }
        __syncthreads();
        if (tid == 0) {
            float m = -INFINITY;
            for (int j = 0; j < d; ++j) m = fmaxf(m, alds[j]);
            float den = 0.f;
            for (int j = 0; j < d; ++j) den += __expf(alds[j] - m);
            minv[0] = m; minv[1] = 1.f / (den + 1e-16f);
        }
        __syncthreads();
        if (tid < d) alds[tid] = __expf(alds[tid] - minv[0]) * minv[1];
        __syncthreads();
    } else {
        if (tid == 0) {
            float adn = ad2[n];
            float m = -INFINITY;
            for (int j = s; j < t; ++j) {
                float v = as2[src[perm[j]]] + adn;
                v = v > 0.f ? v : 0.2f * v;
                m = fmaxf(m, v);
            }
            float den = 0.f;
            for (int j = s; j < t; ++j) {
                float v = as2[src[perm[j]]] + adn;
                v = v > 0.f ? v : 0.2f * v;
                den += __expf(v - m);
            }
            float inv = 1.f / (den + 1e-16f);
            for (int j = s; j < t; ++j) {
                int e = perm[j];
                float v = as2[src[e]] + adn;
                v = v > 0.f ? v : 0.2f * v;
                e2g[e] = __expf(v - m) * inv;
            }
        }
        __syncthreads();
    }

    int j = tid;
    float4 acc = make_float4(0.f, 0.f, 0.f, 0.f);
    int k = s;
    for (; k + 1 < t; k += 2) {
        int e0 = perm[k], e1 = perm[k + 1];
        float a = big ? e2g[e0] : alds[k - s];
        float b = big ? e2g[e1] : alds[k + 1 - s];
        ushort4 u0 = featb[(size_t)src[e0] * D4 + j];
        ushort4 u1 = featb[(size_t)src[e1] * D4 + j];
        acc.x += a * bfu(u0.x) + b * bfu(u1.x);
        acc.y += a * bfu(u0.y) + b * bfu(u1.y);
        acc.z += a * bfu(u0.z) + b * bfu(u1.z);
        acc.w += a * bfu(u0.w) + b * bfu(u1.w);
    }
    if (k < t) {
        int e0 = perm[k];
        float a = big ? e2g[e0] : alds[k - s];
        ushort4 u0 = featb[(size_t)src[e0] * D4 + j];
        acc.x += a * bfu(u0.x); acc.y += a * bfu(u0.y);
        acc.z += a * bfu(u0.z); acc.w += a * bfu(u0.w);
    }
    float4 b = bias4[j];
    acc.x += b.x; acc.y += b.y; acc.z += b.z; acc.w += b.w;
    out4[(size_t)n * D4 + j] = acc;
}

// ---------------- transpose + fp32->bf16 ----------------
__global__ void transpose_bf16_kernel(const float* __restrict__ src, __hip_bfloat16* __restrict__ dst,
                                      int R, int Cc) {
    __shared__ float tile[32][33];
    int bx = blockIdx.x * 32;
    int by = blockIdx.y * 32;
    int tx = threadIdx.x, ty = threadIdx.y;  // 32 x 8
    #pragma unroll
    for (int i = 0; i < 32; i += 8)
        tile[ty + i][tx] = src[(size_t)(by + ty + i) * Cc + (bx + tx)];
    __syncthreads();
    #pragma unroll
    for (int i = 0; i < 32; i += 8)
        dst[(size_t)(bx + ty + i) * R + (by + tx)] = __float2bfloat16(tile[tx][ty + i]);
}

// ---------------- fused: h2 = p0+p1 (split-K S=2) -> bf16; as2/ad2 = h2 . a_s2 / a_d2 ----------------
__global__ __launch_bounds__(192) void reduce_dot_kernel(
    const float4* __restrict__ parts,  // [2][N][192]
    const float4* __restrict__ as_w, const float4* __restrict__ ad_w,
    ushort4* __restrict__ h2b,         // [N][192] bf16 out
    float* __restrict__ as_out, float* __restrict__ ad_out, int NC4) {
    int n = blockIdx.x;
    int j = threadIdx.x;
    size_t idx = (size_t)n * 192 + j;
    float4 a = parts[idx];
    float4 p1 = parts[(size_t)NC4 + idx];
    a.x += p1.x; a.y += p1.y; a.z += p1.z; a.w += p1.w;
    ushort4 st;
    st.x = bf16_bits(a.x); st.y = bf16_bits(a.y);
    st.z = bf16_bits(a.z); st.w = bf16_bits(a.w);
    h2b[idx] = st;
    float4 ws = as_w[j], wd = ad_w[j];
    float ss = a.x * ws.x + a.y * ws.y + a.z * ws.z + a.w * ws.w;
    float sd = a.x * wd.x + a.y * wd.y + a.z * wd.z + a.w * wd.w;
    #pragma unroll
    for (int off = 32; off > 0; off >>= 1) {
        ss += __shfl_down(ss, off, 64);
        sd += __shfl_down(sd, off, 64);
    }
    __shared__ float red_s[3], red_d[3];
    int wv = j >> 6, lane = j & 63;
    if (lane == 0) { red_s[wv] = ss; red_d[wv] = sd; }
    __syncthreads();
    if (j == 0) {
        as_out[n] = red_s[0] + red_s[1] + red_s[2];
        ad_out[n] = red_d[0] + red_d[1] + red_d[2];
    }
}

// ---------------- bf16 MFMA GEMM, 256x256 tile, 8-phase counted-vmcnt schedule ----------------
// C[M,N] = A[M,K] @ BT[N,K]^T.  BM=BN=256, BK=64, 512 threads (8 waves, 2Mx4N),
// 128 KiB double-buffered LDS, XOR bank-swizzle on pre-swizzled global source + ds_read,
// ONE barrier per phase, s_waitcnt vmcnt counted (never 0 mid-loop), setprio around MFMA.
// PANEL-AFFINITY mapping: all GY blocks sharing a B panel (bx,bz) run on ONE XCD
// concurrently -> B panel stays L2-resident (GEMM1: 393 KB, GEMM2: 1.57 MB << 4 MB/XCD),
// halving the L3 staging feed. group = xcd + 8*batch; (bx,bz) = group; by = member.
// Launch grid = 256 * ceil(GX*GZ/8); surplus blocks early-exit.
__device__ inline void gload_lds16(const void* g, void* l) {
    __builtin_amdgcn_global_load_lds((const __attribute__((address_space(1))) unsigned int*)g,
                                     (__attribute__((address_space(3))) unsigned int*)l, 16, 0, 0);
}

#define FENCE() asm volatile("" ::: "memory")
#define BAR() do { FENCE(); __builtin_amdgcn_s_barrier(); FENCE(); } while (0)
#define WAIT_LGKM() asm volatile("s_waitcnt lgkmcnt(0)" ::: "memory")
#define WAIT_LGKM_VM6() asm volatile("s_waitcnt lgkmcnt(0) vmcnt(6)" ::: "memory")
#define WAIT_VM4() asm volatile("s_waitcnt vmcnt(4)" ::: "memory")
#define WAIT_VM0() asm volatile("s_waitcnt vmcnt(0)" ::: "memory")

// stage half h (128 rows) of K-tile kt into buffer b (2 x global_load_lds, 16B/lane)
#define STAGE_A(b, h, kt) do { \
    const __hip_bfloat16* _s = gA0 + (size_t)(h) * 2 * lstrA + (size_t)(kt) * 64; \
    short* _d = dA + (b) * 16384 + (h) * 8192; \
    gload_lds16(_s, _d); \
    gload_lds16(_s + lstrA, _d + 4096); \
} while (0)

#define STAGE_B(b, h, kt) do { \
    const __hip_bfloat16* _s = gB0 + (size_t)(h) * 2 * lstrB + (size_t)(kt) * 64; \
    short* _d = dB + (b) * 16384 + (h) * 8192; \
    gload_lds16(_s, _d); \
    gload_lds16(_s + lstrB, _d + 4096); \
} while (0)

// load A fragments for M-quadrant MQ from buffer b (8 x ds_read_b128, swizzled)
#define LOAD_A(b, MQ) do { \
    const short* _p = Asb + (b) * 16384 + arb + (MQ) * (128 * 64); \
    _Pragma("unroll") for (int mi = 0; mi < 4; ++mi) { \
        af[mi][0] = *(const s16x8*)(_p + mi * (16 * 64) + csw0); \
        af[mi][1] = *(const s16x8*)(_p + mi * (16 * 64) + csw1); \
    } \
} while (0)

// load B fragments for N-quadrant NQ from buffer b (4 x ds_read_b128, swizzled)
#define LOAD_B(b, NQ) do { \
    const short* _p = Bsb + (b) * 16384 + brb + (NQ) * (128 * 64); \
    _Pragma("unroll") for (int ni = 0; ni < 2; ++ni) { \
        bfr[NQ][ni][0] = *(const s16x8*)(_p + ni * (16 * 64) + csw0); \
        bfr[NQ][ni][1] = *(const s16x8*)(_p + ni * (16 * 64) + csw1); \
    } \
} while (0)

#define MMA(MQ, NQ) do { \
    __builtin_amdgcn_s_setprio(1); \
    _Pragma("unroll") for (int ks = 0; ks < 2; ++ks) \
        _Pragma("unroll") for (int mi = 0; mi < 4; ++mi) \
            _Pragma("unroll") for (int ni = 0; ni < 2; ++ni) \
                acc[MQ][NQ][mi][ni] = __builtin_amdgcn_mfma_f32_16x16x32_bf16( \
                    af[ti_ ? mi : mi][ks], bfr[NQ][ni][ks], acc[MQ][NQ][mi][ni], 0, 0, 0); \
    __builtin_amdgcn_s_setprio(0); \
} while (0)

__global__ __launch_bounds__(512, 2) void gemm256_kernel(
    const __hip_bfloat16* __restrict__ A,   // [M][lda]
    const __hip_bfloat16* __restrict__ BT,  // [N][ldb]
    int lda, int ldb, int ldc,
    int K, int kofs_per_z,
    const float* __restrict__ bias,
    __hip_bfloat16* __restrict__ Cb,        // bf16 out or null
    float* __restrict__ Cf,                 // fp32 out (used if Cb==null)
    int flags,                              // 1 = elu
    long bsA, long bsBT, long bsC, long bsBias,
    int GX, int GY, int GZ) {
    extern __shared__ __align__(16) short lds[];
    short* Asb = lds;            // [2][256][64] = 32768 shorts = 64 KiB
    short* Bsb = lds + 32768;    // [2][256][64]

    // ---- panel-affinity mapping: one B panel (bx,bz) per XCD per batch ----
    int lin = blockIdx.x;
    int xcd = lin & 7;
    int slot = lin >> 3;
    int batch = slot >> 5;      // 32 members per batch
    int member = slot & 31;
    int group = xcd + 8 * batch;
    if (group >= GX * GZ || member >= GY) return;
    int bx = group % GX;
    int bz = group / GX;
    int by = member;

    const int ti_ = 0;  // (macro artifact, constant)

    int kofs = bz * kofs_per_z;
    A += (size_t)bz * bsA;
    BT += (size_t)bz * bsBT;
    if (Cb) Cb += (size_t)bz * bsC;
    else    Cf += (size_t)bz * bsC;
    if (bias) bias += (size_t)bz * bsBias;

    int tid = threadIdx.x;
    int lane = tid & 63;
    int wid = tid >> 6;
    int wm = wid >> 2;      // 0..1
    int wn = wid & 3;       // 0..3
    int ml = lane & 15;
    int g  = lane >> 4;     // 0..3

    int row0 = by * 256;
    int col0 = bx * 256;

    // --- staging addresses (pre-swizzled global source, linear LDS dest) ---
    int sr = tid >> 3;                  // row 0..63 within 64-row quarter
    int scl = (tid & 7) ^ (sr & 7);     // swizzled logical 16B-chunk
    const __hip_bfloat16* gA0 = A + (size_t)(row0 + sr) * lda + kofs + scl * 8;
    const __hip_bfloat16* gB0 = BT + (size_t)(col0 + sr) * ldb + kofs + scl * 8;
    size_t lstrA = (size_t)64 * lda;
    size_t lstrB = (size_t)64 * ldb;
    short* dA = Asb + tid * 8;
    short* dB = Bsb + tid * 8;

    // --- fragment read addressing (swizzled chunk = logical ^ (row&7)) ---
    int arb = (wm * 64 + ml) * 64;      // A row base (shorts)
    int brb = (wn * 32 + ml) * 64;      // B row base (shorts)
    int csw0 = ((g) ^ (ml & 7)) * 8;        // ks=0 chunk offset (shorts)
    int csw1 = ((4 + g) ^ (ml & 7)) * 8;    // ks=1

    f32x4 acc[2][2][4][2];
    #pragma unroll
    for (int a0 = 0; a0 < 2; ++a0)
    #pragma unroll
    for (int b0 = 0; b0 < 2; ++b0)
    #pragma unroll
    for (int c0 = 0; c0 < 4; ++c0)
    #pragma unroll
    for (int d0 = 0; d0 < 2; ++d0) acc[a0][b0][c0][d0] = (f32x4){0.f, 0.f, 0.f, 0.f};

    s16x8 af[4][2];
    s16x8 bfr[2][2][2];

    int nkt = K / 64;

    // prologue: tile0 full (buf0) + tile1 A0,B0,A1 (buf1) = 14 insts; leave 6 in flight
    STAGE_A(0, 0, 0); STAGE_B(0, 0, 0); STAGE_A(0, 1, 0); STAGE_B(0, 1, 0);
    STAGE_A(1, 0, 1); STAGE_B(1, 0, 1); STAGE_A(1, 1, 1);
    asm volatile("s_waitcnt vmcnt(6)" ::: "memory");
    BAR();

    for (int i = 0; i < nkt / 2; ++i) {
        int t1 = 2 * i + 1, t2 = 2 * i + 2, t3 = 2 * i + 3;
        bool p2 = t2 < nkt, p3 = t3 < nkt;
        // phase 1: tile 2i quadrant (0,0)
        LOAD_A(0, 0); LOAD_B(0, 0);
        STAGE_B(1, 1, t1);
        MMA(0, 0); WAIT_LGKM(); BAR();
        // phase 2: (0,1)
        LOAD_B(0, 1);
        if (p2) STAGE_A(0, 0, t2);
        MMA(0, 1); WAIT_LGKM(); BAR();
        // phase 3: (1,0)
        LOAD_A(0, 1);
        if (p2) STAGE_B(0, 0, t2);
        MMA(1, 0); WAIT_LGKM(); BAR();
        // phase 4: (1,1) + K-tile boundary (counted vmcnt, never 0)
        if (p2) STAGE_A(0, 1, t2);
        MMA(1, 1); WAIT_LGKM_VM6(); BAR();
        // phase 5: tile 2i+1 quadrant (0,0)
        LOAD_A(1, 0); LOAD_B(1, 0);
        if (p2) STAGE_B(0, 1, t2);
        MMA(0, 0); WAIT_LGKM(); BAR();
        // phase 6: (0,1)
        LOAD_B(1, 1);
        if (p3) STAGE_A(1, 0, t3);
        MMA(0, 1); WAIT_LGKM(); BAR();
        // phase 7: (1,0)
        LOAD_A(1, 1);
        if (p3) STAGE_B(1, 0, t3);
        MMA(1, 0); WAIT_LGKM(); BAR();
        // phase 8: (1,1) + K-tile boundary
        if (p3) STAGE_A(1, 1, t3);
        MMA(1, 1); WAIT_LGKM_VM6(); BAR();
    }

    // epilogue: C/D mapping col=lane&15, row=(lane>>4)*4+r (verified layout)
    #pragma unroll
    for (int mq = 0; mq < 2; ++mq)
    #pragma unroll
    for (int nq = 0; nq < 2; ++nq)
    #pragma unroll
    for (int mi = 0; mi < 4; ++mi)
    #pragma unroll
    for (int ni = 0; ni < 2; ++ni) {
        int row = row0 + mq * 128 + wm * 64 + mi * 16 + g * 4;
        int col = col0 + nq * 128 + wn * 32 + ni * 16 + ml;
        float bv = bias ? bias[col] : 0.f;
        #pragma unroll
        for (int r = 0; r < 4; ++r) {
            float v = acc[mq][nq][mi][ni][r] + bv;
            if (flags & 1) {
                float ev = __expf(v) - 1.f;  // elu (select, no branch)
                v = v > 0.f ? v : ev;
            }
            size_t idx = (size_t)(row + r) * ldc + col;
            if (Cb) Cb[idx] = __float2bfloat16(v);
            else    Cf[idx] = v;
        }
    }
}

// ---------------- launch ----------------
extern "C" void kernel_launch(void* const* d_in, const int* in_sizes, int n_in,
                              void* d_out, int out_size, void* d_ws, size_t ws_size,
                              hipStream_t stream) {
    const int N = 8192, E = 65536, DIN = 768, C = 768, H1n = 8;
    const int HC1 = H1n * C;  // 6144

    const float* x    = (const float*)d_in[0];
    const float* W1   = (const float*)d_in[1];
    const float* a_s1 = (const float*)d_in[2];
    const float* a_d1 = (const float*)d_in[3];
    const float* b1   = (const float*)d_in[4];
    const float* W2   = (const float*)d_in[5];
    const float* a_s2 = (const float*)d_in[6];
    const float* a_d2 = (const float*)d_in[7];
    const float* b2   = (const float*)d_in[8];
    const int*   edges = (const int*)d_in[9];
    const int* src = edges;
    const int* dst = edges + E;

    // ---- workspace layout (~248.7 MB) ----
    char* w = (char*)d_ws;
    auto alloc = [&](size_t bytes) -> void* {
        void* p = (void*)w;
        w += (bytes + 255) & ~(size_t)255;
        return p;
    };
    __hip_bfloat16* zAB = (__hip_bfloat16*)alloc((size_t)N * HC1 * 2);      // 100.7 MB
    __hip_bfloat16* o1  = (__hip_bfloat16*)alloc((size_t)N * HC1 * 2);      // 100.7 MB
    ushort4* xb4        = (ushort4*)alloc((size_t)N * DIN * 2);             // 12.6 MB
    ushort4* h2b        = (ushort4*)alloc((size_t)N * C * 2);               // 12.6 MB
    __hip_bfloat16* W1T = (__hip_bfloat16*)alloc((size_t)HC1 * DIN * 2);    // 9.4 MB
    __hip_bfloat16* W2T = (__hip_bfloat16*)alloc((size_t)C * HC1 * 2);      // 9.4 MB
    float* wv      = (float*)alloc((size_t)16 * DIN * 4);
    float* as1     = (float*)alloc((size_t)N * H1n * 4);
    float* ad1     = (float*)alloc((size_t)N * H1n * 4);
    float* e1      = (float*)alloc((size_t)E * H1n * 4);   // fallback alpha (deg > MAXD)
    float* as2     = (float*)alloc((size_t)N * 4);
    float* ad2     = (float*)alloc((size_t)N * 4);
    float* e2      = (float*)alloc((size_t)E * 4);         // fallback alpha (deg > MAXD)
    int*   counts  = (int*)alloc((size_t)N * 4);
    int*   cursor  = (int*)alloc((size_t)N * 4);
    int*   row_ofs = (int*)alloc((size_t)(N + 1) * 4);
    int*   perm    = (int*)alloc((size_t)E * 4);

    // split-K partials for GEMM2 (S=2) alias zAB (dead after GEMM1; 2*25.2 <= 100.7 MB)
    float* partials = (float*)zAB;

    // 128 KiB dynamic LDS for the 256^2 GEMM
    (void)hipFuncSetAttribute((const void*)gemm256_kernel,
                              hipFuncAttributeMaxDynamicSharedMemorySize, 131072);

    // ---- CSR by dst ----
    zero2_kernel<<<(N + 255) / 256, 256, 0, stream>>>(counts, cursor, N);
    hist_kernel<<<(E + 255) / 256, 256, 0, stream>>>(dst, counts, E);
    scan_kernel<<<1, SCAN_T, 0, stream>>>(counts, row_ofs, N);
    scatter_kernel<<<(E + 255) / 256, 256, 0, stream>>>(dst, row_ofs, cursor, perm, E);

    // ---- x -> bf16 gather table ----
    {
        int n4 = N * DIN / 4;
        f32_to_bf16_kernel<<<(n4 + 255) / 256, 256, 0, stream>>>((const float4*)x, xb4, n4);
    }

    // ---- weight transforms (bf16, transposed) ----
    {
        dim3 b(32, 8);
        dim3 g1(HC1 / 32, DIN / 32);
        transpose_bf16_kernel<<<g1, b, 0, stream>>>(W1, W1T, DIN, HC1);
        dim3 g2(C / 32, HC1 / 32);
        transpose_bf16_kernel<<<g2, b, 0, stream>>>(W2, W2T, HC1, C);
    }

    // ---- Layer 1 attention coefficients ----
    wvec_kernel<<<(H1n * DIN * 64 + 255) / 256, 256, 0, stream>>>(W1, a_s1, a_d1, wv, wv + 8 * DIN, DIN, H1n, C);
    alpha16_kernel<<<N / 4, 256, 0, stream>>>((const float4*)x, wv, as1, ad1);

    // ---- fused softmax + 8-head aggregation: xb -> zAB (bf16) ----
    agg8_fused_kernel<<<N, 192, 0, stream>>>(xb4, as1, ad1, src, row_ofs, perm,
                                             e1, zAB, DIN / 4);

    // ---- GEMM1: all 8 heads; o1 = ELU(z @ W1 + b1) ----
    {
        int GX = C / 256, GY = N / 256, GZ = H1n;   // 3 x 32 x 8
        int groups = GX * GZ;                        // 24
        int batches = (groups + 7) / 8;              // 3
        gemm256_kernel<<<256 * batches, 512, 131072, stream>>>(
            zAB, W1T,
            HC1, DIN, HC1,
            DIN, /*kofs_per_z=*/0,
            b1, o1, nullptr, /*flags=*/1,
            /*bsA=*/C, /*bsBT=*/(long)C * DIN, /*bsC=*/C, /*bsBias=*/C,
            GX, GY, GZ);
    }
    // ---- GEMM2: K=6144 split-K S=2 into partials (aliasing zAB) ----
    {
        int GX = C / 256, GY = N / 256, GZ = 2;     // 3 x 32 x 2
        int Kslice = HC1 / 2;                        // 3072 -> 48 K-tiles/block
        int groups = GX * GZ;                        // 6
        int batches = (groups + 7) / 8;              // 1
        gemm256_kernel<<<256 * batches, 512, 131072, stream>>>(
            o1, W2T,
            HC1, HC1, C,
            Kslice, /*kofs_per_z=*/Kslice,
            nullptr, nullptr, partials, /*flags=*/0,
            0, 0, /*bsC=*/(long)N * C, 0,
            GX, GY, GZ);
    }

    // ---- fused: h2b = bf16(p0 + p1) ; as2/ad2 = h2 . a_s2 / a_d2 ----
    reduce_dot_kernel<<<N, 192, 0, stream>>>((const float4*)partials, (const float4*)a_s2,
                                             (const float4*)a_d2, h2b, as2, ad2, N * C / 4);

    // ---- fused layer-2 softmax + output aggregation ----
    out_fused_kernel<<<N, 192, 0, stream>>>(h2b, as2, ad2, src, row_ofs, perm,
                                            e2, (const float4*)b2, (float4*)d_out, C / 4);
}

// Round 5
// 406.164 us; speedup vs baseline: 3.6655x; 1.0905x over previous
//
#include <hip/hip_runtime.h>
#include <hip/hip_bf16.h>
#include <math.h>

typedef __attribute__((ext_vector_type(4))) float f32x4;
typedef __attribute__((ext_vector_type(8))) short s16x8;

#define MAXD 192  // fast-path degree cap for fused softmax (LDS alpha buffer)

// ---------------- CSR-by-dst construction ----------------

__global__ void zero2_kernel(int* __restrict__ a, int* __restrict__ b, int n) {
    int i = blockIdx.x * blockDim.x + threadIdx.x;
    if (i < n) { a[i] = 0; b[i] = 0; }
}

__global__ void hist_kernel(const int* __restrict__ dst, int* __restrict__ counts, int E) {
    int e = blockIdx.x * blockDim.x + threadIdx.x;
    if (e < E) atomicAdd(&counts[dst[e]], 1);
}

#define SCAN_T 1024
__global__ __launch_bounds__(SCAN_T) void scan_kernel(const int* __restrict__ counts,
                                                      int* __restrict__ row_ofs, int Nn) {
    __shared__ int part[SCAN_T];
    int tid = threadIdx.x;
    int chunk = Nn / SCAN_T;
    int base = tid * chunk;
    int sum = 0;
    for (int i = 0; i < chunk; ++i) sum += counts[base + i];
    part[tid] = sum;
    __syncthreads();
    for (int off = 1; off < SCAN_T; off <<= 1) {
        int v = part[tid];
        int u = (tid >= off) ? part[tid - off] : 0;
        __syncthreads();
        part[tid] = v + u;
        __syncthreads();
    }
    if (tid == SCAN_T - 1) row_ofs[Nn] = part[tid];
    int acc = part[tid] - sum;  // exclusive prefix
    for (int i = 0; i < chunk; ++i) { row_ofs[base + i] = acc; acc += counts[base + i]; }
}

__global__ void scatter_kernel(const int* __restrict__ dst, const int* __restrict__ row_ofs,
                               int* __restrict__ cursor, int* __restrict__ perm, int E) {
    int e = blockIdx.x * blockDim.x + threadIdx.x;
    if (e < E) {
        int d = dst[e];
        int pos = atomicAdd(&cursor[d], 1);
        perm[row_ofs[d] + pos] = e;
    }
}

// ---------------- helpers ----------------
__device__ inline unsigned short bf16_bits(float f) {
    __hip_bfloat16 b = __float2bfloat16(f);
    return *reinterpret_cast<unsigned short*>(&b);
}
__device__ inline float bfu(unsigned short u) {
    return __uint_as_float(((unsigned)u) << 16);
}

// ---------------- w_as/w_ad precompute ----------------
__global__ void wvec_kernel(const float* __restrict__ W, const float* __restrict__ a_s,
                            const float* __restrict__ a_d, float* __restrict__ w_as,
                            float* __restrict__ w_ad, int DIN, int H, int C) {
    int gid = blockIdx.x * blockDim.x + threadIdx.x;
    int wid = gid >> 6;
    int lane = threadIdx.x & 63;
    if (wid >= H * DIN) return;
    int h = wid / DIN, i = wid % DIN;
    const float* wp = W + (size_t)i * H * C + (size_t)h * C;
    const float* sp = a_s + (size_t)h * C;
    const float* dp = a_d + (size_t)h * C;
    float ss = 0.f, sd = 0.f;
    for (int c = lane; c < C; c += 64) {
        float v = wp[c];
        ss += v * sp[c];
        sd += v * dp[c];
    }
    #pragma unroll
    for (int off = 32; off > 0; off >>= 1) {
        ss += __shfl_down(ss, off, 64);
        sd += __shfl_down(sd, off, 64);
    }
    if (lane == 0) { w_as[wid] = ss; w_ad[wid] = sd; }
}

// ---------------- layer-1 alpha dots + xb4 emission; one wave per node ----------------
__global__ __launch_bounds__(256) void alpha16_kernel(const float4* __restrict__ x4,
                                                      const float* __restrict__ wv,
                                                      float* __restrict__ as_out,
                                                      float* __restrict__ ad_out,
                                                      ushort4* __restrict__ xb4) {
    __shared__ float ws[16 * 768];
    int tid = threadIdx.x;
    #pragma unroll
    for (int i = 0; i < 12; ++i)
        ((float4*)ws)[tid + i * 256] = ((const float4*)wv)[tid + i * 256];
    __syncthreads();
    int wvid = tid >> 6, lane = tid & 63;
    int n = blockIdx.x * 4 + wvid;
    float4 xr[3];
    #pragma unroll
    for (int r = 0; r < 3; ++r) xr[r] = x4[(size_t)n * 192 + lane + 64 * r];
    // emit bf16 copy of x (saves a separate conversion pass)
    #pragma unroll
    for (int r = 0; r < 3; ++r) {
        ushort4 o;
        o.x = bf16_bits(xr[r].x); o.y = bf16_bits(xr[r].y);
        o.z = bf16_bits(xr[r].z); o.w = bf16_bits(xr[r].w);
        xb4[(size_t)n * 192 + lane + 64 * r] = o;
    }
    #pragma unroll
    for (int j = 0; j < 16; ++j) {
        const float4* wj = (const float4*)(ws + j * 768);
        float s = 0.f;
        #pragma unroll
        for (int r = 0; r < 3; ++r) {
            float4 wc = wj[lane + 64 * r];
            s += xr[r].x * wc.x + xr[r].y * wc.y + xr[r].z * wc.z + xr[r].w * wc.w;
        }
        #pragma unroll
        for (int off = 32; off > 0; off >>= 1) s += __shfl_down(s, off, 64);
        if (lane == 0) {
            if (j < 8) as_out[n * 8 + j] = s;
            else       ad_out[n * 8 + (j - 8)] = s;
        }
    }
}

// ---------------- FUSED: per-node softmax (8 heads) + 8-head aggregation -> zAB bf16 ----------------
__global__ __launch_bounds__(192) void agg8_fused_kernel(
    const ushort4* __restrict__ xb4,  // [N][192] bf16 x (gather-halved)
    const float* __restrict__ as1,    // [N][8]
    const float* __restrict__ ad1,    // [N][8]
    const int* __restrict__ src,
    const int* __restrict__ row_ofs,
    const int* __restrict__ perm,
    float* __restrict__ e1g,          // [E][8] global fallback alpha
    __hip_bfloat16* __restrict__ zAB, // [N][8*768]
    int D4) {
    __shared__ float alds[MAXD * 8];
    __shared__ float mh[8], dh[8];
    int n = blockIdx.x;
    int s = row_ofs[n], t = row_ofs[n + 1];
    int d = t - s;
    int tid = threadIdx.x;
    bool big = d > MAXD;
    if (!big) {
        int eh = tid & 7, ei = tid >> 3;  // ei in 0..23
        float adn = ad1[n * 8 + eh];
        for (int base = 0; base < d; base += 24) {
            int j = base + ei;
            if (j < d) {
                int e = perm[s + j];
                float v = as1[src[e] * 8 + eh] + adn;
                v = v > 0.f ? v : 0.2f * v;
                alds[j * 8 + eh] = v;
            }
        }
        __syncthreads();
        if (tid < 8) {
            float m = -INFINITY;
            for (int j = 0; j < d; ++j) m = fmaxf(m, alds[j * 8 + tid]);
            float den = 0.f;
            for (int j = 0; j < d; ++j) den += __expf(alds[j * 8 + tid] - m);
            mh[tid] = m; dh[tid] = 1.f / (den + 1e-16f);
        }
        __syncthreads();
        for (int base = 0; base < d; base += 24) {
            int j = base + ei;
            if (j < d) alds[j * 8 + eh] = __expf(alds[j * 8 + eh] - mh[eh]) * dh[eh];
        }
        __syncthreads();
    } else {
        if (tid < 8) {
            int hh = tid;
            float adn = ad1[n * 8 + hh];
            float m = -INFINITY;
            for (int j = s; j < t; ++j) {
                float v = as1[src[perm[j]] * 8 + hh] + adn;
                v = v > 0.f ? v : 0.2f * v;
                m = fmaxf(m, v);
            }
            float den = 0.f;
            for (int j = s; j < t; ++j) {
                float v = as1[src[perm[j]] * 8 + hh] + adn;
                v = v > 0.f ? v : 0.2f * v;
                den += __expf(v - m);
            }
            float inv = 1.f / (den + 1e-16f);
            for (int j = s; j < t; ++j) {
                int e = perm[j];
                float v = as1[src[e] * 8 + hh] + adn;
                v = v > 0.f ? v : 0.2f * v;
                e1g[(size_t)e * 8 + hh] = __expf(v - m) * inv;
            }
        }
        __syncthreads();
    }

    // aggregation: thread j handles bf16x4 column j for all 8 heads
    int j = tid;
    float4 acc[8];
    #pragma unroll
    for (int h = 0; h < 8; ++h) acc[h] = make_float4(0.f, 0.f, 0.f, 0.f);
    int k = s;
    for (; k + 1 < t; k += 2) {
        int e0 = perm[k], e1 = perm[k + 1];
        ushort4 u0 = xb4[(size_t)src[e0] * D4 + j];
        ushort4 u1 = xb4[(size_t)src[e1] * D4 + j];
        float4 v0 = make_float4(bfu(u0.x), bfu(u0.y), bfu(u0.z), bfu(u0.w));
        float4 v1 = make_float4(bfu(u1.x), bfu(u1.y), bfu(u1.z), bfu(u1.w));
        const float* a0 = big ? &e1g[(size_t)e0 * 8] : &alds[(k - s) * 8];
        const float* a1 = big ? &e1g[(size_t)e1 * 8] : &alds[(k + 1 - s) * 8];
        #pragma unroll
        for (int h = 0; h < 8; ++h) {
            float a = a0[h], b = a1[h];
            acc[h].x += a * v0.x + b * v1.x;
            acc[h].y += a * v0.y + b * v1.y;
            acc[h].z += a * v0.z + b * v1.z;
            acc[h].w += a * v0.w + b * v1.w;
        }
    }
    if (k < t) {
        int e0 = perm[k];
        ushort4 u0 = xb4[(size_t)src[e0] * D4 + j];
        float4 v0 = make_float4(bfu(u0.x), bfu(u0.y), bfu(u0.z), bfu(u0.w));
        const float* a0 = big ? &e1g[(size_t)e0 * 8] : &alds[(k - s) * 8];
        #pragma unroll
        for (int h = 0; h < 8; ++h) {
            float a = a0[h];
            acc[h].x += a * v0.x; acc[h].y += a * v0.y;
            acc[h].z += a * v0.z; acc[h].w += a * v0.w;
        }
    }
    int D = D4 * 4;
    #pragma unroll
    for (int h = 0; h < 8; ++h) {
        size_t o = (size_t)n * 8 * D + (size_t)h * D + j * 4;
        ushort4 st;
        st.x = bf16_bits(acc[h].x); st.y = bf16_bits(acc[h].y);
        st.z = bf16_bits(acc[h].z); st.w = bf16_bits(acc[h].w);
        *reinterpret_cast<ushort4*>(&zAB[o]) = st;
    }
}

// ---------------- FUSED: layer-2 softmax (H=1) + output aggregation (+bias) ----------------
__global__ __launch_bounds__(192) void out_fused_kernel(
    const ushort4* __restrict__ featb,  // h2b [N][192] bf16 (gather-halved)
    const float* __restrict__ as2,      // [N]
    const float* __restrict__ ad2,      // [N]
    const int* __restrict__ src,
    const int* __restrict__ row_ofs,
    const int* __restrict__ perm,
    float* __restrict__ e2g,            // [E] global fallback alpha
    const float4* __restrict__ bias4,
    float4* __restrict__ out4, int D4) {
    __shared__ float alds[MAXD];
    __shared__ float minv[2];
    int n = blockIdx.x;
    int s = row_ofs[n], t = row_ofs[n + 1];
    int d = t - s;
    int tid = threadIdx.x;
    bool big = d > MAXD;
    if (!big) {
        float adn = ad2[n];
        if (tid < d) {
            float v = as2[src[perm[s + tid]]] + adn;
            v = v > 0.f ? v : 0.2f * v;
            alds[tid] = v;
        }
        __syncthreads();
        if (tid == 0) {
            float m = -INFINITY;
            for (int j = 0; j < d; ++j) m = fmaxf(m, alds[j]);
            float den = 0.f;
            for (int j = 0; j < d; ++j) den += __expf(alds[j] - m);
            minv[0] = m; minv[1] = 1.f / (den + 1e-16f);
        }
        __syncthreads();
        if (tid < d) alds[tid] = __expf(alds[tid] - minv[0]) * minv[1];
        __syncthreads();
    } else {
        if (tid == 0) {
            float adn = ad2[n];
            float m = -INFINITY;
            for (int j = s; j < t; ++j) {
                float v = as2[src[perm[j]]] + adn;
                v = v > 0.f ? v : 0.2f * v;
                m = fmaxf(m, v);
            }
            float den = 0.f;
            for (int j = s; j < t; ++j) {
                float v = as2[src[perm[j]]] + adn;
                v = v > 0.f ? v : 0.2f * v;
                den += __expf(v - m);
            }
            float inv = 1.f / (den + 1e-16f);
            for (int j = s; j < t; ++j) {
                int e = perm[j];
                float v = as2[src[e]] + adn;
                v = v > 0.f ? v : 0.2f * v;
                e2g[e] = __expf(v - m) * inv;
            }
        }
        __syncthreads();
    }

    int j = tid;
    float4 acc = make_float4(0.f, 0.f, 0.f, 0.f);
    int k = s;
    for (; k + 1 < t; k += 2) {
        int e0 = perm[k], e1 = perm[k + 1];
        float a = big ? e2g[e0] : alds[k - s];
        float b = big ? e2g[e1] : alds[k + 1 - s];
        ushort4 u0 = featb[(size_t)src[e0] * D4 + j];
        ushort4 u1 = featb[(size_t)src[e1] * D4 + j];
        acc.x += a * bfu(u0.x) + b * bfu(u1.x);
        acc.y += a * bfu(u0.y) + b * bfu(u1.y);
        acc.z += a * bfu(u0.z) + b * bfu(u1.z);
        acc.w += a * bfu(u0.w) + b * bfu(u1.w);
    }
    if (k < t) {
        int e0 = perm[k];
        float a = big ? e2g[e0] : alds[k - s];
        ushort4 u0 = featb[(size_t)src[e0] * D4 + j];
        acc.x += a * bfu(u0.x); acc.y += a * bfu(u0.y);
        acc.z += a * bfu(u0.z); acc.w += a * bfu(u0.w);
    }
    float4 b = bias4[j];
    acc.x += b.x; acc.y += b.y; acc.z += b.z; acc.w += b.w;
    out4[(size_t)n * D4 + j] = acc;
}

// ---------------- transpose + fp32->bf16 ----------------
__global__ void transpose_bf16_kernel(const float* __restrict__ src, __hip_bfloat16* __restrict__ dst,
                                      int R, int Cc) {
    __shared__ float tile[32][33];
    int bx = blockIdx.x * 32;
    int by = blockIdx.y * 32;
    int tx = threadIdx.x, ty = threadIdx.y;  // 32 x 8
    #pragma unroll
    for (int i = 0; i < 32; i += 8)
        tile[ty + i][tx] = src[(size_t)(by + ty + i) * Cc + (bx + tx)];
    __syncthreads();
    #pragma unroll
    for (int i = 0; i < 32; i += 8)
        dst[(size_t)(bx + ty + i) * R + (by + tx)] = __float2bfloat16(tile[tx][ty + i]);
}

// ---------------- fused: h2 = p0+p1 (split-K S=2) -> bf16; as2/ad2 = h2 . a_s2 / a_d2 ----------------
__global__ __launch_bounds__(192) void reduce_dot_kernel(
    const float4* __restrict__ parts,  // [2][N][192]
    const float4* __restrict__ as_w, const float4* __restrict__ ad_w,
    ushort4* __restrict__ h2b,         // [N][192] bf16 out
    float* __restrict__ as_out, float* __restrict__ ad_out, int NC4) {
    int n = blockIdx.x;
    int j = threadIdx.x;
    size_t idx = (size_t)n * 192 + j;
    float4 a = parts[idx];
    float4 p1 = parts[(size_t)NC4 + idx];
    a.x += p1.x; a.y += p1.y; a.z += p1.z; a.w += p1.w;
    ushort4 st;
    st.x = bf16_bits(a.x); st.y = bf16_bits(a.y);
    st.z = bf16_bits(a.z); st.w = bf16_bits(a.w);
    h2b[idx] = st;
    float4 ws = as_w[j], wd = ad_w[j];
    float ss = a.x * ws.x + a.y * ws.y + a.z * ws.z + a.w * ws.w;
    float sd = a.x * wd.x + a.y * wd.y + a.z * wd.z + a.w * wd.w;
    #pragma unroll
    for (int off = 32; off > 0; off >>= 1) {
        ss += __shfl_down(ss, off, 64);
        sd += __shfl_down(sd, off, 64);
    }
    __shared__ float red_s[3], red_d[3];
    int wv = j >> 6, lane = j & 63;
    if (lane == 0) { red_s[wv] = ss; red_d[wv] = sd; }
    __syncthreads();
    if (j == 0) {
        as_out[n] = red_s[0] + red_s[1] + red_s[2];
        ad_out[n] = red_d[0] + red_d[1] + red_d[2];
    }
}

// ---------------- shared GEMM machinery ----------------
__device__ inline void gload_lds16(const void* g, void* l) {
    __builtin_amdgcn_global_load_lds((const __attribute__((address_space(1))) unsigned int*)g,
                                     (__attribute__((address_space(3))) unsigned int*)l, 16, 0, 0);
}

#define FENCE() asm volatile("" ::: "memory")
#define BAR() do { FENCE(); __builtin_amdgcn_s_barrier(); FENCE(); } while (0)
#define WAIT_LGKM() asm volatile("s_waitcnt lgkmcnt(0)" ::: "memory")
#define WAIT_LGKM_VM6() asm volatile("s_waitcnt lgkmcnt(0) vmcnt(6)" ::: "memory")
#define WAIT_VM0() asm volatile("s_waitcnt vmcnt(0)" ::: "memory")

// ---------------- bf16 MFMA GEMM, 256x256 tile, 8-phase counted-vmcnt (round-2 best config) ----------------
#define STAGE_A(b, h, kt) do { \
    const __hip_bfloat16* _s = gA0 + (size_t)(h) * 2 * lstrA + (size_t)(kt) * 64; \
    short* _d = dA + (b) * 16384 + (h) * 8192; \
    gload_lds16(_s, _d); \
    gload_lds16(_s + lstrA, _d + 4096); \
} while (0)

#define STAGE_B(b, h, kt) do { \
    const __hip_bfloat16* _s = gB0 + (size_t)(h) * 2 * lstrB + (size_t)(kt) * 64; \
    short* _d = dB + (b) * 16384 + (h) * 8192; \
    gload_lds16(_s, _d); \
    gload_lds16(_s + lstrB, _d + 4096); \
} while (0)

#define LOAD_A(b, MQ) do { \
    const short* _p = Asb + (b) * 16384 + arb + (MQ) * (128 * 64); \
    _Pragma("unroll") for (int mi = 0; mi < 4; ++mi) { \
        af[mi][0] = *(const s16x8*)(_p + mi * (16 * 64) + csw0); \
        af[mi][1] = *(const s16x8*)(_p + mi * (16 * 64) + csw1); \
    } \
} while (0)

#define LOAD_B(b, NQ) do { \
    const short* _p = Bsb + (b) * 16384 + brb + (NQ) * (128 * 64); \
    _Pragma("unroll") for (int ni = 0; ni < 2; ++ni) { \
        bfr[NQ][ni][0] = *(const s16x8*)(_p + ni * (16 * 64) + csw0); \
        bfr[NQ][ni][1] = *(const s16x8*)(_p + ni * (16 * 64) + csw1); \
    } \
} while (0)

#define MMA(MQ, NQ) do { \
    __builtin_amdgcn_s_setprio(1); \
    _Pragma("unroll") for (int ks = 0; ks < 2; ++ks) \
        _Pragma("unroll") for (int mi = 0; mi < 4; ++mi) \
            _Pragma("unroll") for (int ni = 0; ni < 2; ++ni) \
                acc[MQ][NQ][mi][ni] = __builtin_amdgcn_mfma_f32_16x16x32_bf16( \
                    af[mi][ks], bfr[NQ][ni][ks], acc[MQ][NQ][mi][ni], 0, 0, 0); \
    __builtin_amdgcn_s_setprio(0); \
} while (0)

__global__ __launch_bounds__(512, 2) void gemm256_kernel(
    const __hip_bfloat16* __restrict__ A,   // [M][lda]
    const __hip_bfloat16* __restrict__ BT,  // [N][ldb]
    int lda, int ldb, int ldc,
    int K, int kofs_per_z,
    const float* __restrict__ bias,
    __hip_bfloat16* __restrict__ Cb,        // bf16 out or null
    float* __restrict__ Cf,                 // fp32 out (used if Cb==null)
    int flags,                              // 1 = elu
    long bsA, long bsBT, long bsC, long bsBias,
    int GX, int GY) {
    extern __shared__ __align__(16) short lds[];
    short* Asb = lds;            // [2][256][64]
    short* Bsb = lds + 32768;    // [2][256][64]

    int lin = blockIdx.x;
    int xcd = lin & 7;
    int u = lin >> 3;
    int bx = u % GX;
    int cg = u / GX;
    int cc = cg * 8 + xcd;
    int by = cc % GY;
    int bz = cc / GY;

    int kofs = bz * kofs_per_z;
    A += (size_t)bz * bsA;
    BT += (size_t)bz * bsBT;
    if (Cb) Cb += (size_t)bz * bsC;
    else    Cf += (size_t)bz * bsC;
    if (bias) bias += (size_t)bz * bsBias;

    int tid = threadIdx.x;
    int lane = tid & 63;
    int wid = tid >> 6;
    int wm = wid >> 2;
    int wn = wid & 3;
    int ml = lane & 15;
    int g  = lane >> 4;

    int row0 = by * 256;
    int col0 = bx * 256;

    int sr = tid >> 3;
    int scl = (tid & 7) ^ (sr & 7);
    const __hip_bfloat16* gA0 = A + (size_t)(row0 + sr) * lda + kofs + scl * 8;
    const __hip_bfloat16* gB0 = BT + (size_t)(col0 + sr) * ldb + kofs + scl * 8;
    size_t lstrA = (size_t)64 * lda;
    size_t lstrB = (size_t)64 * ldb;
    short* dA = Asb + tid * 8;
    short* dB = Bsb + tid * 8;

    int arb = (wm * 64 + ml) * 64;
    int brb = (wn * 32 + ml) * 64;
    int csw0 = ((g) ^ (ml & 7)) * 8;
    int csw1 = ((4 + g) ^ (ml & 7)) * 8;

    f32x4 acc[2][2][4][2];
    #pragma unroll
    for (int a0 = 0; a0 < 2; ++a0)
    #pragma unroll
    for (int b0 = 0; b0 < 2; ++b0)
    #pragma unroll
    for (int c0 = 0; c0 < 4; ++c0)
    #pragma unroll
    for (int d0 = 0; d0 < 2; ++d0) acc[a0][b0][c0][d0] = (f32x4){0.f, 0.f, 0.f, 0.f};

    s16x8 af[4][2];
    s16x8 bfr[2][2][2];

    int nkt = K / 64;

    STAGE_A(0, 0, 0); STAGE_B(0, 0, 0); STAGE_A(0, 1, 0); STAGE_B(0, 1, 0);
    STAGE_A(1, 0, 1); STAGE_B(1, 0, 1); STAGE_A(1, 1, 1);
    asm volatile("s_waitcnt vmcnt(6)" ::: "memory");
    BAR();

    for (int i = 0; i < nkt / 2; ++i) {
        int t1 = 2 * i + 1, t2 = 2 * i + 2, t3 = 2 * i + 3;
        bool p2 = t2 < nkt, p3 = t3 < nkt;
        LOAD_A(0, 0); LOAD_B(0, 0);
        STAGE_B(1, 1, t1);
        MMA(0, 0); WAIT_LGKM(); BAR();
        LOAD_B(0, 1);
        if (p2) STAGE_A(0, 0, t2);
        MMA(0, 1); WAIT_LGKM(); BAR();
        LOAD_A(0, 1);
        if (p2) STAGE_B(0, 0, t2);
        MMA(1, 0); WAIT_LGKM(); BAR();
        if (p2) STAGE_A(0, 1, t2);
        MMA(1, 1); WAIT_LGKM_VM6(); BAR();
        LOAD_A(1, 0); LOAD_B(1, 0);
        if (p2) STAGE_B(0, 1, t2);
        MMA(0, 0); WAIT_LGKM(); BAR();
        LOAD_B(1, 1);
        if (p3) STAGE_A(1, 0, t3);
        MMA(0, 1); WAIT_LGKM(); BAR();
        LOAD_A(1, 1);
        if (p3) STAGE_B(1, 0, t3);
        MMA(1, 0); WAIT_LGKM(); BAR();
        if (p3) STAGE_A(1, 1, t3);
        MMA(1, 1); WAIT_LGKM_VM6(); BAR();
    }

    #pragma unroll
    for (int mq = 0; mq < 2; ++mq)
    #pragma unroll
    for (int nq = 0; nq < 2; ++nq)
    #pragma unroll
    for (int mi = 0; mi < 4; ++mi)
    #pragma unroll
    for (int ni = 0; ni < 2; ++ni) {
        int row = row0 + mq * 128 + wm * 64 + mi * 16 + g * 4;
        int col = col0 + nq * 128 + wn * 32 + ni * 16 + ml;
        float bv = bias ? bias[col] : 0.f;
        #pragma unroll
        for (int r = 0; r < 4; ++r) {
            float v = acc[mq][nq][mi][ni][r] + bv;
            if (flags & 1) {
                float ev = __expf(v) - 1.f;
                v = v > 0.f ? v : ev;
            }
            size_t idx = (size_t)(row + r) * ldc + col;
            if (Cb) Cb[idx] = __float2bfloat16(v);
            else    Cf[idx] = v;
        }
    }
}

// ---------------- bf16 MFMA GEMM, 256x192 tile (full-machine GEMM2 variant) ----------------
// BM=256, BN=192, BK=64, 512 threads (8 waves 2Mx4N, wave covers 128 rows x 48 cols).
// LDS 112 KiB (A [2][256][64], B [2][192][64]); 7 global_load_lds per K-tile.
// 2-phase loop: stage-next(7) -> {LOAD A(mq0)+B, MFMA} -> {LOAD A(mq1), MFMA} -> vmcnt(0)+BAR.
// Stages have a full iteration (~1500+ cy) to land, so the boundary drain is cheap.
#define SA192(b, kt) do { \
    _Pragma("unroll") for (int q = 0; q < 4; ++q) \
        gload_lds16(gA0 + (size_t)q * lstrA + (size_t)(kt) * 64, dA + (b) * 16384 + q * 4096); \
} while (0)

#define SB192(b, kt) do { \
    _Pragma("unroll") for (int q = 0; q < 3; ++q) \
        gload_lds16(gB0 + (size_t)q * lstrB + (size_t)(kt) * 64, dB + (b) * 12288 + q * 4096); \
} while (0)

#define LA192(b, MQ) do { \
    const short* _p = Asb + (b) * 16384 + arb + (MQ) * (128 * 64); \
    _Pragma("unroll") for (int mi = 0; mi < 4; ++mi) { \
        af[mi][0] = *(const s16x8*)(_p + mi * (16 * 64) + csw0); \
        af[mi][1] = *(const s16x8*)(_p + mi * (16 * 64) + csw1); \
    } \
} while (0)

#define LB192(b) do { \
    const short* _p = Bsb + (b) * 12288 + brb; \
    _Pragma("unroll") for (int ni = 0; ni < 3; ++ni) { \
        bfr[ni][0] = *(const s16x8*)(_p + ni * (16 * 64) + csw0); \
        bfr[ni][1] = *(const s16x8*)(_p + ni * (16 * 64) + csw1); \
    } \
} while (0)

#define MM192(MQ) do { \
    __builtin_amdgcn_s_setprio(1); \
    _Pragma("unroll") for (int ks = 0; ks < 2; ++ks) \
        _Pragma("unroll") for (int mi = 0; mi < 4; ++mi) \
            _Pragma("unroll") for (int ni = 0; ni < 3; ++ni) \
                acc[MQ][mi][ni] = __builtin_amdgcn_mfma_f32_16x16x32_bf16( \
                    af[mi][ks], bfr[ni][ks], acc[MQ][mi][ni], 0, 0, 0); \
    __builtin_amdgcn_s_setprio(0); \
} while (0)

__global__ __launch_bounds__(512, 2) void gemm192_kernel(
    const __hip_bfloat16* __restrict__ A,   // [M][lda]
    const __hip_bfloat16* __restrict__ BT,  // [N][ldb]
    int lda, int ldb, int ldc,
    int K, int kofs_per_z,
    float* __restrict__ Cf,                 // fp32 out
    long bsC,
    int GX, int GY) {
    extern __shared__ __align__(16) short lds[];
    short* Asb = lds;            // [2][256][64] = 32768 shorts
    short* Bsb = lds + 32768;    // [2][192][64] = 24576 shorts

    int lin = blockIdx.x;
    int xcd = lin & 7;
    int u = lin >> 3;
    int bx = u % GX;
    int cg = u / GX;
    int cc = cg * 8 + xcd;
    int by = cc % GY;
    int bz = cc / GY;

    int kofs = bz * kofs_per_z;
    Cf += (size_t)bz * bsC;

    int tid = threadIdx.x;
    int lane = tid & 63;
    int wid = tid >> 6;
    int wm = wid >> 2;      // 0..1
    int wn = wid & 3;       // 0..3
    int ml = lane & 15;
    int g  = lane >> 4;

    int row0 = by * 256;
    int col0 = bx * 192;

    int sr = tid >> 3;
    int scl = (tid & 7) ^ (sr & 7);
    const __hip_bfloat16* gA0 = A + (size_t)(row0 + sr) * lda + kofs + scl * 8;
    const __hip_bfloat16* gB0 = BT + (size_t)(col0 + sr) * ldb + kofs + scl * 8;
    size_t lstrA = (size_t)64 * lda;
    size_t lstrB = (size_t)64 * ldb;
    short* dA = Asb + tid * 8;
    short* dB = Bsb + tid * 8;

    int arb = (wm * 64 + ml) * 64;
    int brb = (wn * 48 + ml) * 64;
    int csw0 = ((g) ^ (ml & 7)) * 8;
    int csw1 = ((4 + g) ^ (ml & 7)) * 8;

    f32x4 acc[2][4][3];
    #pragma unroll
    for (int a0 = 0; a0 < 2; ++a0)
    #pragma unroll
    for (int b0 = 0; b0 < 4; ++b0)
    #pragma unroll
    for (int c0 = 0; c0 < 3; ++c0) acc[a0][b0][c0] = (f32x4){0.f, 0.f, 0.f, 0.f};

    s16x8 af[4][2];
    s16x8 bfr[3][2];

    int nkt = K / 64;  // 48

    SA192(0, 0); SB192(0, 0);
    WAIT_VM0();
    BAR();

    for (int t = 0; t < nkt; ++t) {
        int cur = t & 1;
        if (t + 1 < nkt) { SA192(cur ^ 1, t + 1); SB192(cur ^ 1, t + 1); }
        LA192(cur, 0); LB192(cur);
        WAIT_LGKM();
        MM192(0);
        LA192(cur, 1);
        WAIT_LGKM();
        MM192(1);
        WAIT_VM0();   // next buffer fully landed (stages had the whole iteration)
        BAR();
    }

    #pragma unroll
    for (int mq = 0; mq < 2; ++mq)
    #pragma unroll
    for (int mi = 0; mi < 4; ++mi)
    #pragma unroll
    for (int ni = 0; ni < 3; ++ni) {
        int row = row0 + mq * 128 + wm * 64 + mi * 16 + g * 4;
        int col = col0 + wn * 48 + ni * 16 + ml;
        #pragma unroll
        for (int r = 0; r < 4; ++r) {
            Cf[(size_t)(row + r) * ldc + col] = acc[mq][mi][ni][r];
        }
    }
}

// ---------------- launch ----------------
extern "C" void kernel_launch(void* const* d_in, const int* in_sizes, int n_in,
                              void* d_out, int out_size, void* d_ws, size_t ws_size,
                              hipStream_t stream) {
    const int N = 8192, E = 65536, DIN = 768, C = 768, H1n = 8;
    const int HC1 = H1n * C;  // 6144

    const float* x    = (const float*)d_in[0];
    const float* W1   = (const float*)d_in[1];
    const float* a_s1 = (const float*)d_in[2];
    const float* a_d1 = (const float*)d_in[3];
    const float* b1   = (const float*)d_in[4];
    const float* W2   = (const float*)d_in[5];
    const float* a_s2 = (const float*)d_in[6];
    const float* a_d2 = (const float*)d_in[7];
    const float* b2   = (const float*)d_in[8];
    const int*   edges = (const int*)d_in[9];
    const int* src = edges;
    const int* dst = edges + E;

    // ---- workspace layout ----
    char* w = (char*)d_ws;
    auto alloc = [&](size_t bytes) -> void* {
        void* p = (void*)w;
        w += (bytes + 255) & ~(size_t)255;
        return p;
    };
    __hip_bfloat16* zAB = (__hip_bfloat16*)alloc((size_t)N * HC1 * 2);      // 100.7 MB
    __hip_bfloat16* o1  = (__hip_bfloat16*)alloc((size_t)N * HC1 * 2);      // 100.7 MB
    ushort4* xb4        = (ushort4*)alloc((size_t)N * DIN * 2);             // 12.6 MB
    ushort4* h2b        = (ushort4*)alloc((size_t)N * C * 2);               // 12.6 MB
    __hip_bfloat16* W1T = (__hip_bfloat16*)alloc((size_t)HC1 * DIN * 2);    // 9.4 MB
    __hip_bfloat16* W2T = (__hip_bfloat16*)alloc((size_t)C * HC1 * 2);      // 9.4 MB
    float* wv      = (float*)alloc((size_t)16 * DIN * 4);
    float* as1     = (float*)alloc((size_t)N * H1n * 4);
    float* ad1     = (float*)alloc((size_t)N * H1n * 4);
    float* e1      = (float*)alloc((size_t)E * H1n * 4);
    float* as2     = (float*)alloc((size_t)N * 4);
    float* ad2     = (float*)alloc((size_t)N * 4);
    float* e2      = (float*)alloc((size_t)E * 4);
    int*   counts  = (int*)alloc((size_t)N * 4);
    int*   cursor  = (int*)alloc((size_t)N * 4);
    int*   row_ofs = (int*)alloc((size_t)(N + 1) * 4);
    int*   perm    = (int*)alloc((size_t)E * 4);

    // split-K partials for GEMM2 (S=2) alias zAB (dead after GEMM1)
    float* partials = (float*)zAB;

    (void)hipFuncSetAttribute((const void*)gemm256_kernel,
                              hipFuncAttributeMaxDynamicSharedMemorySize, 131072);
    (void)hipFuncSetAttribute((const void*)gemm192_kernel,
                              hipFuncAttributeMaxDynamicSharedMemorySize, 131072);

    // ---- CSR by dst ----
    zero2_kernel<<<(N + 255) / 256, 256, 0, stream>>>(counts, cursor, N);
    hist_kernel<<<(E + 255) / 256, 256, 0, stream>>>(dst, counts, E);
    scan_kernel<<<1, SCAN_T, 0, stream>>>(counts, row_ofs, N);
    scatter_kernel<<<(E + 255) / 256, 256, 0, stream>>>(dst, row_ofs, cursor, perm, E);

    // ---- weight transforms (bf16, transposed) ----
    {
        dim3 b(32, 8);
        dim3 g1(HC1 / 32, DIN / 32);
        transpose_bf16_kernel<<<g1, b, 0, stream>>>(W1, W1T, DIN, HC1);
        dim3 g2(C / 32, HC1 / 32);
        transpose_bf16_kernel<<<g2, b, 0, stream>>>(W2, W2T, HC1, C);
    }

    // ---- Layer 1 attention coefficients (+ xb4 emission) ----
    wvec_kernel<<<(H1n * DIN * 64 + 255) / 256, 256, 0, stream>>>(W1, a_s1, a_d1, wv, wv + 8 * DIN, DIN, H1n, C);
    alpha16_kernel<<<N / 4, 256, 0, stream>>>((const float4*)x, wv, as1, ad1, xb4);

    // ---- fused softmax + 8-head aggregation: xb -> zAB (bf16) ----
    agg8_fused_kernel<<<N, 192, 0, stream>>>(xb4, as1, ad1, src, row_ofs, perm,
                                             e1, zAB, DIN / 4);

    // ---- GEMM1: all 8 heads; o1 = ELU(z @ W1 + b1) ----
    {
        int GX = C / 256, GY = N / 256;  // 3 x 32 x 8 heads = 768 blocks
        gemm256_kernel<<<GX * GY * H1n, 512, 131072, stream>>>(
            zAB, W1T,
            HC1, DIN, HC1,
            DIN, /*kofs_per_z=*/0,
            b1, o1, nullptr, /*flags=*/1,
            /*bsA=*/C, /*bsBT=*/(long)C * DIN, /*bsC=*/C, /*bsBias=*/C,
            GX, GY);
    }
    // ---- GEMM2: K=6144 split-K S=2 into partials, BN=192, full machine (256 blocks) ----
    {
        int GX = C / 192, GY = N / 256;  // 4 x 32 x 2 = 256 blocks
        int Kslice = HC1 / 2;            // 3072 -> 48 K-tiles/block
        gemm192_kernel<<<GX * GY * 2, 512, 131072, stream>>>(
            o1, W2T,
            HC1, HC1, C,
            Kslice, /*kofs_per_z=*/Kslice,
            partials, /*bsC=*/(long)N * C,
            GX, GY);
    }

    // ---- fused: h2b = bf16(p0 + p1) ; as2/ad2 = h2 . a_s2 / a_d2 ----
    reduce_dot_kernel<<<N, 192, 0, stream>>>((const float4*)partials, (const float4*)a_s2,
                                             (const float4*)a_d2, h2b, as2, ad2, N * C / 4);

    // ---- fused layer-2 softmax + output aggregation ----
    out_fused_kernel<<<N, 192, 0, stream>>>(h2b, as2, ad2, src, row_ofs, perm,
                                            e2, (const float4*)b2, (float4*)d_out, C / 4);
}